// Round 4
// baseline (3677.499 us; speedup 1.0000x reference)
//
#include <hip/hip_runtime.h>
#include <math.h>

#define EPS 1e-6f

namespace {

typedef unsigned short u16;
typedef unsigned int u32;
typedef __bf16 bf16x8 __attribute__((ext_vector_type(8)));
typedef float f32x4 __attribute__((ext_vector_type(4)));
typedef u16 u16x8 __attribute__((ext_vector_type(8)));

constexpr int Bb = 4, Ss = 512, Dd = 512, Ii = 1024, Cc = 64;
constexpr int nCk = 8, RowsC = 256, RowsAll = 2048;
constexpr int NWG = 256;

__device__ __forceinline__ float sigmoidf_(float x) { return 1.f / (1.f + expf(-x)); }
__device__ __forceinline__ float siluf_(float x)    { return x / (1.f + expf(-x)); }

__device__ __forceinline__ u16 f2bf(float f) {
  u32 u = __float_as_uint(f);
  u32 r = u + 0x7fffu + ((u >> 16) & 1u);
  return (u16)(r >> 16);
}

__device__ __forceinline__ void llds16(const u16* g, u16* l) {
  __builtin_amdgcn_global_load_lds((__attribute__((address_space(1))) void*)g,
                                   (__attribute__((address_space(3))) void*)l,
                                   16, 0, 0);
}

__device__ __forceinline__ float wave_sum(float v) {
  #pragma unroll
  for (int m = 32; m > 0; m >>= 1) v += __shfl_xor(v, m, 64);
  return v;
}

// ---------------- workspace carve (host+device identical) ----------------
struct WS {
  float *w0c, *Sw0, *w1c, *Sw1, *lnc, *Sln, *tmpK, *Krows, *Vrows,
        *Ybuf, *gyr, *Z0, *alv, *thv, *etv, *wBv, *wEv, *scal, *Qb, *Yr;
  u16 *xcb, *wqb, *wkvb, *w0b, *w1b, *w1tb, *Kb, *KT, *Hb, *Ht,
      *dYb, *dYtW, *dYtE, *dHtW, *dHtE, *Qbb, *Hrb;
};
__host__ __device__ inline WS mkws(char* base) {
  WS s; char* p = base + 256;
#define CF(nm, n) s.nm = (float*)p; p += (size_t)(n) * 4;
#define CU(nm, n) s.nm = (u16*)p;   p += (size_t)(n) * 2;
  CF(w0c, Ii*Dd) CF(Sw0, Ii*Dd) CF(w1c, Dd*Ii) CF(Sw1, Dd*Ii)
  CF(lnc, Dd) CF(Sln, Dd)
  CF(tmpK, (size_t)RowsAll*Dd) CF(Krows, (size_t)RowsAll*Dd) CF(Vrows, (size_t)RowsAll*Dd)
  CF(Ybuf, RowsC*Dd) CF(gyr, RowsC*Dd) CF(Z0, RowsC*Ii)
  CF(alv, Ss) CF(thv, Ss) CF(etv, Ss) CF(wBv, nCk*RowsC) CF(wEv, nCk*RowsC) CF(scal, nCk*4)
  CF(Qb, (size_t)RowsAll*Dd) CF(Yr, (size_t)RowsAll*Dd)
  CU(xcb, (size_t)RowsAll*Dd) CU(wqb, Dd*Dd) CU(wkvb, (size_t)Ii*Dd)
  CU(w0b, (size_t)Ii*Dd) CU(w1b, (size_t)Dd*Ii) CU(w1tb, (size_t)Ii*Dd)
  CU(Kb, (size_t)RowsAll*Dd) CU(KT, (size_t)RowsAll*Dd)
  CU(Hb, RowsC*Ii) CU(Ht, RowsC*Ii)
  CU(dYb, RowsC*Dd) CU(dYtW, RowsC*Dd) CU(dYtE, RowsC*Dd)
  CU(dHtW, RowsC*Ii) CU(dHtE, RowsC*Ii)
  CU(Qbb, (size_t)RowsAll*Dd) CU(Hrb, (size_t)RowsAll*Ii)
#undef CF
#undef CU
  return s;
}

// ---------------- grid barrier (all 256 WGs co-resident) ----------------
__device__ __forceinline__ void gbar(u32* cnt, u32* gen) {
  __syncthreads();
  if (threadIdx.x == 0) {
    __threadfence();   // agent-scope release: flush this WG's phase writes
    u32 g = __hip_atomic_load(gen, __ATOMIC_RELAXED, __HIP_MEMORY_SCOPE_AGENT);
    u32 a = __hip_atomic_fetch_add(cnt, 1u, __ATOMIC_ACQ_REL, __HIP_MEMORY_SCOPE_AGENT);
    if (a == (u32)(NWG - 1)) {
      __hip_atomic_store(cnt, 0u, __ATOMIC_RELAXED, __HIP_MEMORY_SCOPE_AGENT);
      __hip_atomic_fetch_add(gen, 1u, __ATOMIC_RELEASE, __HIP_MEMORY_SCOPE_AGENT);
    } else {
      long sp = 0;
      while (__hip_atomic_load(gen, __ATOMIC_ACQUIRE, __HIP_MEMORY_SCOPE_AGENT) == g) {
        __builtin_amdgcn_s_sleep(2);
        if (++sp > (1L << 22)) break;   // bounded: corrupt instead of hang
      }
    }
    __threadfence();   // agent-scope acquire: invalidate stale cached lines
  }
  __syncthreads();
}

// ---------------- 64x64 MFMA tile (one job) ----------------
// EPI: 0 C0=v | 1 KV split | 2 C0=v,Cb=bf(silu),CbT=bf(silu)^T
//      3 dh=v*silu'(Z): CbT=bf(dh*wB), CbT2=bf(dh*wE) | 4 Cb=bf(silu)
template<int EPI>
__device__ void tile64(
    u16* smA, u16* smB,
    const u16* __restrict__ A, const u16* __restrict__ Bt,
    int K, int N, int bm, int bn,
    float* C0, float* C1, u16* Cb, u16* CbT, u16* CbT2,
    const float* Z, const float* wB, const float* wE, int trM)
{
  const int tid = threadIdx.x;
  const int l = tid & 63, lr = l & 15, lq = l >> 4;
  const int w = tid >> 6, wr = w >> 1, wc = w & 1;

  f32x4 acc[2][2];
  #pragma unroll
  for (int i = 0; i < 2; ++i)
    #pragma unroll
    for (int j = 0; j < 2; ++j) acc[i][j] = f32x4{0.f, 0.f, 0.f, 0.f};

  for (int k0 = 0; k0 < K; k0 += 64) {
    #pragma unroll
    for (int i = 0; i < 2; ++i) {
      int e = i * 256 + tid;
      int r = e >> 3, c = (e & 7) ^ (r & 7);
      llds16(A  + (size_t)(bm + r) * K + k0 + c * 8, smA + e * 8);
      llds16(Bt + (size_t)(bn + r) * K + k0 + c * 8, smB + e * 8);
    }
    __syncthreads();
    #pragma unroll
    for (int kk = 0; kk < 2; ++kk) {
      bf16x8 av[2], bv[2];
      #pragma unroll
      for (int m = 0; m < 2; ++m) {
        int r = wr * 32 + m * 16 + lr;
        int c = (kk * 4 + lq) ^ (r & 7);
        av[m] = *reinterpret_cast<const bf16x8*>(&smA[r * 64 + c * 8]);
      }
      #pragma unroll
      for (int n = 0; n < 2; ++n) {
        int r = wc * 32 + n * 16 + lr;
        int c = (kk * 4 + lq) ^ (r & 7);
        bv[n] = *reinterpret_cast<const bf16x8*>(&smB[r * 64 + c * 8]);
      }
      #pragma unroll
      for (int m = 0; m < 2; ++m)
        #pragma unroll
        for (int n = 0; n < 2; ++n)
          acc[m][n] = __builtin_amdgcn_mfma_f32_16x16x32_bf16(av[m], bv[n], acc[m][n], 0, 0, 0);
    }
    __syncthreads();
  }

  #pragma unroll
  for (int m = 0; m < 2; ++m) {
    int gr0 = bm + wr * 32 + m * 16 + lq * 4;
    float wbq[4], weq[4];
    if (EPI == 3) {
      #pragma unroll
      for (int q = 0; q < 4; ++q) { wbq[q] = wB[gr0 + q]; weq[q] = wE[gr0 + q]; }
    }
    #pragma unroll
    for (int n = 0; n < 2; ++n) {
      int gc = bn + wc * 32 + n * 16 + lr;
      ushort4 t1, t2;
      #pragma unroll
      for (int q = 0; q < 4; ++q) {
        float v = acc[m][n][q];
        size_t idx = (size_t)(gr0 + q) * N + gc;
        if (EPI == 0) {
          C0[idx] = v;
        } else if (EPI == 1) {
          if (gc < Dd) C0[(size_t)(gr0 + q) * Dd + gc] = v;
          else         C1[(size_t)(gr0 + q) * Dd + gc - Dd] = siluf_(v);
        } else if (EPI == 2) {
          C0[idx] = v;
          float h = siluf_(v);
          Cb[idx] = f2bf(h);
          ((u16*)&t1)[q] = f2bf(h);
        } else if (EPI == 3) {
          float z = Z[idx];
          float sg = 1.f / (1.f + expf(-z));
          float dh = v * sg * (1.f + z * (1.f - sg));
          ((u16*)&t1)[q] = f2bf(dh * wbq[q]);
          ((u16*)&t2)[q] = f2bf(dh * weq[q]);
        } else if (EPI == 4) {
          Cb[idx] = f2bf(siluf_(v));
        }
      }
      if (EPI == 2) *reinterpret_cast<ushort4*>(&CbT[(size_t)gc * trM + gr0]) = t1;
      if (EPI == 3) {
        *reinterpret_cast<ushort4*>(&CbT[(size_t)gc * trM + gr0]) = t1;
        *reinterpret_cast<ushort4*>(&CbT2[(size_t)gc * trM + gr0]) = t2;
      }
    }
  }
}

// ---------------- dual-weighted grad tile + fused param update ----------------
template<bool TR>
__device__ void gtile64(
    u16* smA, u16* smB, u16* smE,
    const u16* __restrict__ AW, const u16* __restrict__ AE,
    const u16* __restrict__ Bt,
    float* P, float* Sm, u16* Pb, u16* PbT, const float* scal,
    int M, int N, int K, int bm, int bn)
{
  const int tid = threadIdx.x;
  const int l = tid & 63, lr = l & 15, lq = l >> 4;
  const int w = tid >> 6, wr = w >> 1, wc = w & 1;

  f32x4 aM[2][2], aE[2][2];
  #pragma unroll
  for (int i = 0; i < 2; ++i)
    #pragma unroll
    for (int j = 0; j < 2; ++j) {
      aM[i][j] = f32x4{0.f, 0.f, 0.f, 0.f};
      aE[i][j] = f32x4{0.f, 0.f, 0.f, 0.f};
    }

  for (int k0 = 0; k0 < K; k0 += 64) {
    #pragma unroll
    for (int i = 0; i < 2; ++i) {
      int e = i * 256 + tid;
      int r = e >> 3, c = (e & 7) ^ (r & 7);
      llds16(AW + (size_t)(bm + r) * K + k0 + c * 8, smA + e * 8);
      llds16(AE + (size_t)(bm + r) * K + k0 + c * 8, smE + e * 8);
      llds16(Bt + (size_t)(bn + r) * K + k0 + c * 8, smB + e * 8);
    }
    __syncthreads();
    #pragma unroll
    for (int kk = 0; kk < 2; ++kk) {
      bf16x8 awv[2], aev[2], bv[2];
      #pragma unroll
      for (int m = 0; m < 2; ++m) {
        int r = wr * 32 + m * 16 + lr;
        int c = (kk * 4 + lq) ^ (r & 7);
        awv[m] = *reinterpret_cast<const bf16x8*>(&smA[r * 64 + c * 8]);
        aev[m] = *reinterpret_cast<const bf16x8*>(&smE[r * 64 + c * 8]);
      }
      #pragma unroll
      for (int n = 0; n < 2; ++n) {
        int r = wc * 32 + n * 16 + lr;
        int c = (kk * 4 + lq) ^ (r & 7);
        bv[n] = *reinterpret_cast<const bf16x8*>(&smB[r * 64 + c * 8]);
      }
      #pragma unroll
      for (int m = 0; m < 2; ++m)
        #pragma unroll
        for (int n = 0; n < 2; ++n) {
          aM[m][n] = __builtin_amdgcn_mfma_f32_16x16x32_bf16(awv[m], bv[n], aM[m][n], 0, 0, 0);
          aE[m][n] = __builtin_amdgcn_mfma_f32_16x16x32_bf16(aev[m], bv[n], aE[m][n], 0, 0, 0);
        }
    }
    __syncthreads();
  }

  float s0 = scal[0], s1 = scal[1], s2 = scal[2];
  #pragma unroll
  for (int m = 0; m < 2; ++m) {
    int gr0 = bm + wr * 32 + m * 16 + lq * 4;
    #pragma unroll
    for (int n = 0; n < 2; ++n) {
      int gc = bn + wc * 32 + n * 16 + lr;
      ushort4 t1;
      #pragma unroll
      for (int q = 0; q < 4; ++q) {
        size_t idx = (size_t)(gr0 + q) * N + gc;
        float p = P[idx], s = Sm[idx];
        float np = s0 * p + s1 * s - aM[m][n][q];
        float ns = s2 * s - aE[m][n][q];
        P[idx] = np; Sm[idx] = ns;
        Pb[idx] = f2bf(np);
        if (TR) ((u16*)&t1)[q] = f2bf(np);
      }
      if (TR) *reinterpret_cast<ushort4*>(&PbT[(size_t)gc * M + gr0]) = t1;
    }
  }
}

// ---------------- wave-per-row helpers ----------------
__device__ void silurms4(u16* smA, const float* in, float* outf, u16* outb,
                         u16* KTc, const float* nw, int r0, int rloc, bool tr)
{
  const int tid = threadIdx.x, w = tid >> 6, l = tid & 63;
  const int row = r0 + w, d0 = l * 8;
  const float* ir = in + (size_t)row * Dd + d0;
  float v[8];
  *(float4*)&v[0] = *(const float4*)ir;
  *(float4*)&v[4] = *(const float4*)(ir + 4);
  float ss = 0.f;
  #pragma unroll
  for (int j = 0; j < 8; ++j) { v[j] = siluf_(v[j]); ss += v[j] * v[j]; }
  ss = wave_sum(ss);
  float rr = rsqrtf(ss / (float)Dd + EPS);
  float nv[8];
  *(float4*)&nv[0] = *(const float4*)(nw + d0);
  *(float4*)&nv[4] = *(const float4*)(nw + d0 + 4);
  float y[8]; u16x8 pb;
  #pragma unroll
  for (int j = 0; j < 8; ++j) { y[j] = v[j] * rr * nv[j]; pb[j] = f2bf(y[j]); }
  float* orow = outf + (size_t)row * Dd + d0;
  *(float4*)orow       = *(float4*)&y[0];
  *(float4*)(orow + 4) = *(float4*)&y[4];
  *(u16x8*)(outb + (size_t)row * Dd + d0) = pb;
  if (tr) {
    u16* lt = smA;                       // [4][512]
    #pragma unroll
    for (int j = 0; j < 8; ++j) lt[w * Dd + d0 + j] = pb[j];
    __syncthreads();
    for (int d = tid; d < Dd; d += 256) {
      ushort4 pk;
      pk.x = lt[d]; pk.y = lt[Dd + d]; pk.z = lt[2 * Dd + d]; pk.w = lt[3 * Dd + d];
      *reinterpret_cast<ushort4*>(&KTc[(size_t)d * RowsC + rloc]) = pk;
    }
    __syncthreads();
  }
}

__device__ void lossback4(u16* smA, u16* smB,
    const float* Kr, const float* Vr, const float* Y,
    const float* lnc, const float* th, const float* wB, const float* wE,
    u16* dYb, u16* dYtW, u16* dYtE, float* gyr, int j)
{
  u16* lw = smA; u16* le = smB;          // [4][512] each
  const int tid = threadIdx.x, w = tid >> 6, l = tid & 63;
  const int row = j * 4 + w, t = row & 63, d0 = l * 8;
  size_t base = (size_t)row * Dd + d0;

  float y[8], kk[8], vv[8], lv[8];
  *(float4*)&y[0]  = *(const float4*)(Y + base);
  *(float4*)&y[4]  = *(const float4*)(Y + base + 4);
  *(float4*)&kk[0] = *(const float4*)(Kr + base);
  *(float4*)&kk[4] = *(const float4*)(Kr + base + 4);
  *(float4*)&vv[0] = *(const float4*)(Vr + base);
  *(float4*)&vv[4] = *(const float4*)(Vr + base + 4);
  *(float4*)&lv[0] = *(const float4*)(lnc + d0);
  *(float4*)&lv[4] = *(const float4*)(lnc + d0 + 4);

  float ss = 0.f;
  #pragma unroll
  for (int q = 0; q < 8; ++q) ss += y[q] * y[q];
  ss = wave_sum(ss);
  float rr = rsqrtf(ss / (float)Dd + EPS);
  float c = 2.f * th[t] / (float)Dd;

  float g[8], s2 = 0.f;
  #pragma unroll
  for (int q = 0; q < 8; ++q) {
    g[q] = c * ((kk[q] + y[q] * rr * lv[q]) - vv[q]);
    s2 += g[q] * lv[q] * y[q];
  }
  s2 = wave_sum(s2);
  float coef = rr * rr * rr * s2 / (float)Dd;

  float wb = wB[row], we = wE[row];
  u16x8 pb; float gy[8];
  #pragma unroll
  for (int q = 0; q < 8; ++q) {
    float dv = rr * g[q] * lv[q] - coef * y[q];
    pb[q] = f2bf(dv);
    lw[w * Dd + d0 + q] = f2bf(dv * wb);
    le[w * Dd + d0 + q] = f2bf(dv * we);
    gy[q] = g[q] * y[q] * rr;
  }
  *(u16x8*)(dYb + base) = pb;
  *(float4*)(gyr + base)     = *(float4*)&gy[0];
  *(float4*)(gyr + base + 4) = *(float4*)&gy[4];

  __syncthreads();
  int r0 = j * 4;
  for (int d = tid; d < Dd; d += 256) {
    ushort4 pw, pe;
    pw.x = lw[d]; pw.y = lw[Dd + d]; pw.z = lw[2 * Dd + d]; pw.w = lw[3 * Dd + d];
    pe.x = le[d]; pe.y = le[Dd + d]; pe.z = le[2 * Dd + d]; pe.w = le[3 * Dd + d];
    *reinterpret_cast<ushort4*>(&dYtW[(size_t)d * RowsC + r0]) = pw;
    *reinterpret_cast<ushort4*>(&dYtE[(size_t)d * RowsC + r0]) = pe;
  }
  __syncthreads();
}

// ---------------- the persistent megakernel ----------------
__global__ __launch_bounds__(256) void mega_k(
    const float* __restrict__ x,  const float* __restrict__ wq,
    const float* __restrict__ wkw, const float* __restrict__ wvw,
    const float* __restrict__ qn, const float* __restrict__ kn,
    const float* __restrict__ aw, const float* __restrict__ ab,
    const float* __restrict__ tw, const float* __restrict__ tb,
    const float* __restrict__ ew, const float* __restrict__ eb,
    const float* __restrict__ mw0, const float* __restrict__ mw1,
    const float* __restrict__ mln,
    float* __restrict__ out, char* __restrict__ ws)
{
  __shared__ __align__(16) u16 smem[3 * 64 * 64];
  u16* smA = smem; u16* smB = smem + 4096; u16* smE = smem + 8192;
  WS S = mkws(ws);
  u32* bcnt = (u32*)ws; u32* bgen = (u32*)ws + 1;
  const int wg = blockIdx.x, tid = threadIdx.x;
  const int wv = tid >> 6, l = tid & 63;

  // ========== P0: init / dtype conversion ==========
  for (int i = wg * 256 + tid; i < (Dd * Dd) / 4; i += NWG * 256) {
    float4 v = ((const float4*)wq)[i];
    ushort4 o; o.x = f2bf(v.x); o.y = f2bf(v.y); o.z = f2bf(v.z); o.w = f2bf(v.w);
    ((ushort4*)S.wqb)[i] = o;
    v = ((const float4*)wkw)[i];
    o.x = f2bf(v.x); o.y = f2bf(v.y); o.z = f2bf(v.z); o.w = f2bf(v.w);
    ((ushort4*)S.wkvb)[i] = o;
    v = ((const float4*)wvw)[i];
    o.x = f2bf(v.x); o.y = f2bf(v.y); o.z = f2bf(v.z); o.w = f2bf(v.w);
    ((ushort4*)S.wkvb)[i + (Dd * Dd) / 4] = o;
  }
  for (int i = wg * 256 + tid; i < (Ii * Dd) / 4; i += NWG * 256) {
    float4 z4; z4.x = z4.y = z4.z = z4.w = 0.f;
    float4 v = ((const float4*)mw0)[i];
    ((float4*)S.w0c)[i] = v; ((float4*)S.Sw0)[i] = z4;
    ushort4 o; o.x = f2bf(v.x); o.y = f2bf(v.y); o.z = f2bf(v.z); o.w = f2bf(v.w);
    ((ushort4*)S.w0b)[i] = o;
    v = ((const float4*)mw1)[i];
    ((float4*)S.w1c)[i] = v; ((float4*)S.Sw1)[i] = z4;
    o.x = f2bf(v.x); o.y = f2bf(v.y); o.z = f2bf(v.z); o.w = f2bf(v.w);
    ((ushort4*)S.w1b)[i] = o;
  }
  if (wg == 0)
    for (int d = tid; d < Dd; d += 256) { S.lnc[d] = mln[d]; S.Sln[d] = 0.f; }
  {
    u16 (*tt)[66] = (u16(*)[66])smem;    // 64x66 u16 = 8448 B
    for (int j = wg; j < (Dd / 64) * (Ii / 64); j += NWG) {
      int br = (j & 7) * 64, bc = (j >> 3) * 64;
      __syncthreads();
      #pragma unroll
      for (int i = 0; i < 16; ++i) {
        int e = tid + i * 256; int r = e >> 6, c = e & 63;
        tt[r][c] = f2bf(mw1[(size_t)(br + r) * Ii + bc + c]);
      }
      __syncthreads();
      #pragma unroll
      for (int i = 0; i < 16; ++i) {
        int e = tid + i * 256; int rr = e >> 6, cc = e & 63;
        S.w1tb[(size_t)(bc + rr) * Dd + br + cc] = tt[cc][rr];
      }
    }
  }
  gbar(bcnt, bgen);

  // ========== P1: x -> chunk-ordered bf16 + gate dots ==========
  {
    float* red = (float*)smem;
    for (int j = wg; j < Ss; j += NWG) {
      int ci = j >> 6, tk = j & 63;
      const float* xr = x + ((size_t)wv * Ss + j) * Dd + l * 8;
      float v[8], a8[8], t8[8], e8[8];
      *(float4*)&v[0] = *(const float4*)xr;        *(float4*)&v[4] = *(const float4*)(xr + 4);
      *(float4*)&a8[0] = *(const float4*)(aw + l * 8); *(float4*)&a8[4] = *(const float4*)(aw + l * 8 + 4);
      *(float4*)&t8[0] = *(const float4*)(tw + l * 8); *(float4*)&t8[4] = *(const float4*)(tw + l * 8 + 4);
      *(float4*)&e8[0] = *(const float4*)(ew + l * 8); *(float4*)&e8[4] = *(const float4*)(ew + l * 8 + 4);
      u16x8 o; float sa = 0.f, st = 0.f, se = 0.f;
      #pragma unroll
      for (int q = 0; q < 8; ++q) {
        o[q] = f2bf(v[q]);
        sa += v[q] * a8[q]; st += v[q] * t8[q]; se += v[q] * e8[q];
      }
      *(u16x8*)(S.xcb + ((size_t)(ci * RowsC + wv * Cc + tk)) * Dd + l * 8) = o;
      sa = wave_sum(sa); st = wave_sum(st); se = wave_sum(se);
      __syncthreads();
      if (l == 0) { red[wv] = sa; red[4 + wv] = st; red[8 + wv] = se; }
      __syncthreads();
      if (tid == 0) {
        float SA = red[0] + red[1] + red[2] + red[3];
        float ST = red[4] + red[5] + red[6] + red[7];
        float SE = red[8] + red[9] + red[10] + red[11];
        S.alv[j] = sigmoidf_(SA + Bb * ab[0]);
        S.thv[j] = sigmoidf_(ST + Bb * tb[0]) * 0.01f;
        S.etv[j] = sigmoidf_(SE + Bb * eb[0]);
      }
    }
  }
  gbar(bcnt, bgen);

  // ========== P2: gate scans + KV GEMM (all chunks) ==========
  if (wg < nCk && tid == 0) {
    int ci = wg;
    const float* alc = S.alv + ci * Cc;
    const float* etc_ = S.etv + ci * Cc;
    float beta[Cc], wb[Cc], ce[Cc], E[Cc], T[Cc];
    for (int i = 0; i < Cc; ++i) beta[i] = 1.f - alc[i];
    wb[Cc - 1] = 1.f;
    for (int m = Cc - 2; m >= 0; --m) wb[m] = wb[m + 1] * beta[m + 1];
    float bc_last = wb[0] * beta[0];
    float p = 1.f, A = 0.f;
    for (int m = 0; m < Cc; ++m) { p *= etc_[m]; ce[m] = p; A += wb[m] * ce[m]; }
    E[Cc - 1] = 1.f; T[Cc - 1] = 1.f;
    for (int n = Cc - 2; n >= 0; --n) {
      E[n] = E[n + 1] * etc_[n + 1];
      T[n] = wb[n] + etc_[n + 1] * T[n + 1];
    }
    for (int b = 0; b < Bb; ++b)
      for (int t = 0; t < Cc; ++t) {
        S.wBv[ci * RowsC + b * Cc + t] = T[t];
        S.wEv[ci * RowsC + b * Cc + t] = E[t];
      }
    S.scal[ci * 4 + 0] = bc_last; S.scal[ci * 4 + 1] = A; S.scal[ci * 4 + 2] = ce[Cc - 1];
  }
  for (int j = wg; j < 512; j += NWG) {
    int tm = j & 31, tn = j >> 5;
    tile64<1>(smA, smB, S.xcb, S.wkvb, 512, Ii, tm * 64, tn * 64,
              S.tmpK, S.Vrows, nullptr, nullptr, nullptr, nullptr, nullptr, nullptr, 0);
  }
  gbar(bcnt, bgen);

  // ========== P3: silu+rms on all K rows (+KT) ==========
  for (int j = wg; j < 512; j += NWG) {
    int r0 = j * 4, ci = r0 >> 8, rloc = r0 & 255;
    silurms4(smA, S.tmpK, S.Krows, S.Kb, S.KT + (size_t)ci * Dd * RowsC, kn, r0, rloc, true);
  }
  gbar(bcnt, bgen);

  // ========== chunk loop ==========
  for (int ci = 0; ci < nCk; ++ci) {
    const u16* Kbc = S.Kb + (size_t)ci * RowsC * Dd;
    const u16* KTc = S.KT + (size_t)ci * Dd * RowsC;
    const float* Krc = S.Krows + (size_t)ci * RowsC * Dd;
    const float* Vrc = S.Vrows + (size_t)ci * RowsC * Dd;
    const float* scc = S.scal + ci * 4;
    const float* wBc = S.wBv + ci * RowsC;
    const float* wEc = S.wEv + ci * RowsC;
    const float* thc = S.thv + ci * Cc;

    // P4: Z0 = K @ w0^T (+H_bf, +Ht)
    for (int j = wg; j < 64; j += NWG) {
      int tm = j & 3, tn = j >> 2;
      tile64<2>(smA, smB, Kbc, S.w0b, 512, Ii, tm * 64, tn * 64,
                S.Z0, nullptr, S.Hb, S.Ht, nullptr, nullptr, nullptr, nullptr, RowsC);
    }
    gbar(bcnt, bgen);

    // P5: Y = H @ w1^T
    for (int j = wg; j < 32; j += NWG) {
      int tm = j & 3, tn = j >> 2;
      tile64<0>(smA, smB, S.Hb, S.w1b, 1024, Dd, tm * 64, tn * 64,
                S.Ybuf, nullptr, nullptr, nullptr, nullptr, nullptr, nullptr, nullptr, 0);
    }
    gbar(bcnt, bgen);

    // P6: loss backward
    for (int j = wg; j < 64; j += NWG)
      lossback4(smA, smB, Krc, Vrc, S.Ybuf, S.lnc, thc, wBc, wEc,
                S.dYb, S.dYtW, S.dYtE, S.gyr, j);
    gbar(bcnt, bgen);

    // P7: dH = (dY @ w1) * silu'(Z0), transposed+weighted outputs
    for (int j = wg; j < 64; j += NWG) {
      int tm = j & 3, tn = j >> 2;
      tile64<3>(smA, smB, S.dYb, S.w1tb, 512, Ii, tm * 64, tn * 64,
                nullptr, nullptr, nullptr, S.dHtW, S.dHtE, S.Z0, wBc, wEc, RowsC);
    }
    gbar(bcnt, bgen);

    // P8: dual grad GEMMs + fused updates; colsum+ln update piggybacked
    for (int j = wg; j < 256; j += NWG) {
      if (j < 128) {
        int tm = j >> 4, tn = j & 15;
        gtile64<true>(smA, smB, smE, S.dYtW, S.dYtE, S.Ht, S.w1c, S.Sw1,
                      S.w1b, S.w1tb, scc, Dd, Ii, RowsC, tm * 64, tn * 64);
      } else {
        int q = j - 128; int tm = q >> 3, tn = q & 7;
        gtile64<false>(smA, smB, smE, S.dHtW, S.dHtE, KTc, S.w0c, S.Sw0,
                       S.w0b, nullptr, scc, Ii, Dd, RowsC, tm * 64, tn * 64);
      }
    }
    if (wg < 2) {
      int d = wg * 256 + tid;
      float sm = 0.f, se2 = 0.f;
      for (int r = 0; r < RowsC; ++r) {
        float vv = S.gyr[(size_t)r * Dd + d];
        sm += wBc[r] * vv; se2 += wEc[r] * vv;
      }
      float pp = S.lnc[d], sn = S.Sln[d];
      S.lnc[d] = scc[0] * pp + scc[1] * sn - sm;
      S.Sln[d] = scc[2] * sn - se2;
    }
    gbar(bcnt, bgen);
  }

  // ========== retrieval ==========
  // P9: x @ wq^T
  for (int j = wg; j < 256; j += NWG) {
    int tm = j & 31, tn = j >> 5;
    tile64<0>(smA, smB, S.xcb, S.wqb, 512, Dd, tm * 64, tn * 64,
              S.Yr, nullptr, nullptr, nullptr, nullptr, nullptr, nullptr, nullptr, 0);
  }
  gbar(bcnt, bgen);
  // P10: q = rms(silu(.)) * qn
  for (int j = wg; j < 512; j += NWG)
    silurms4(smA, S.Yr, S.Qb, S.Qbb, nullptr, qn, j * 4, 0, false);
  gbar(bcnt, bgen);
  // P11: Hr = silu(q @ w0F^T)
  for (int j = wg; j < 512; j += NWG) {
    int tm = j & 31, tn = j >> 5;
    tile64<4>(smA, smB, S.Qbb, S.w0b, 512, Ii, tm * 64, tn * 64,
              nullptr, nullptr, S.Hrb, nullptr, nullptr, nullptr, nullptr, nullptr, 0);
  }
  gbar(bcnt, bgen);
  // P12: Yr = Hr @ w1F^T
  for (int j = wg; j < 256; j += NWG) {
    int tm = j & 31, tn = j >> 5;
    tile64<0>(smA, smB, S.Hrb, S.w1b, 1024, Dd, tm * 64, tn * 64,
              S.Yr, nullptr, nullptr, nullptr, nullptr, nullptr, nullptr, nullptr, 0);
  }
  gbar(bcnt, bgen);
  // P13: out = q + rms(y) * lnF  (permute back to original layout)
  for (int j = wg; j < 512; j += NWG) {
    int row = j * 4 + wv;
    int ci = row >> 8, wi = row & 255, b = wi >> 6, t = wi & 63;
    const float* yr = S.Yr + (size_t)row * Dd + l * 8;
    float y[8];
    *(float4*)&y[0] = *(const float4*)yr;
    *(float4*)&y[4] = *(const float4*)(yr + 4);
    float ss = 0.f;
    #pragma unroll
    for (int q = 0; q < 8; ++q) ss += y[q] * y[q];
    ss = wave_sum(ss);
    float rr = rsqrtf(ss / (float)Dd + EPS);
    const float* qb = S.Qb + (size_t)row * Dd + l * 8;
    const float* lf = S.lnc + l * 8;
    float o[8];
    #pragma unroll
    for (int q = 0; q < 8; ++q) o[q] = qb[q] + y[q] * rr * lf[q];
    float* ob = out + ((size_t)b * Ss + ci * Cc + t) * Dd + l * 8;
    *(float4*)ob       = *(float4*)&o[0];
    *(float4*)(ob + 4) = *(float4*)&o[4];
  }
}

} // namespace

extern "C" void kernel_launch(void* const* d_in, const int* in_sizes, int n_in,
                              void* d_out, int out_size, void* d_ws, size_t ws_size,
                              hipStream_t stream)
{
  const float* x   = (const float*)d_in[0];
  const float* wq  = (const float*)d_in[1];
  const float* wkw = (const float*)d_in[2];
  const float* wvw = (const float*)d_in[3];
  const float* qn  = (const float*)d_in[4];
  const float* kn  = (const float*)d_in[5];
  const float* aw  = (const float*)d_in[6];
  const float* ab  = (const float*)d_in[7];
  const float* tw  = (const float*)d_in[8];
  const float* tb  = (const float*)d_in[9];
  const float* ew  = (const float*)d_in[10];
  const float* eb  = (const float*)d_in[11];
  const float* mw0 = (const float*)d_in[12];
  const float* mw1 = (const float*)d_in[13];
  const float* mln = (const float*)d_in[14];

  hipMemsetAsync(d_ws, 0, 256, stream);   // barrier counter + generation
  mega_k<<<NWG, 256, 0, stream>>>(x, wq, wkw, wvw, qn, kn, aw, ab, tw, tb,
                                  ew, eb, mw0, mw1, mln,
                                  (float*)d_out, (char*)d_ws);
}

// Round 5
// 471.993 us; speedup vs baseline: 7.7914x; 7.7914x over previous
//
#include <hip/hip_runtime.h>
#include <math.h>

#define EPS 1e-6f

namespace {

typedef unsigned short u16;
typedef unsigned int u32;
typedef __bf16 bf16x8 __attribute__((ext_vector_type(8)));
typedef float f32x4 __attribute__((ext_vector_type(4)));
typedef u16 u16x8 __attribute__((ext_vector_type(8)));

constexpr int Bb = 4, Ss = 512, Dd = 512, Ii = 1024, Cc = 64;
constexpr int nCk = 8, RowsC = 256, RowsAll = 2048;

__device__ __forceinline__ float sigmoidf_(float x) { return 1.f / (1.f + expf(-x)); }
__device__ __forceinline__ float siluf_(float x)    { return x / (1.f + expf(-x)); }

__device__ __forceinline__ u16 f2bf(float f) {
  u32 u = __float_as_uint(f);
  u32 r = u + 0x7fffu + ((u >> 16) & 1u);
  return (u16)(r >> 16);
}

__device__ __forceinline__ void llds16(const u16* g, u16* l) {
  __builtin_amdgcn_global_load_lds((__attribute__((address_space(1))) void*)g,
                                   (__attribute__((address_space(3))) void*)l,
                                   16, 0, 0);
}

__device__ __forceinline__ float wave_sum(float v) {
  #pragma unroll
  for (int m = 32; m > 0; m >>= 1) v += __shfl_xor(v, m, 64);
  return v;
}

__device__ __forceinline__ float block_reduce_sum(float v, float* red) {
  int tid = threadIdx.x;
  red[tid] = v; __syncthreads();
  for (int s = 128; s > 0; s >>= 1) {
    if (tid < s) red[tid] += red[tid + s];
    __syncthreads();
  }
  float r = red[0]; __syncthreads();
  return r;
}

// ---------------- workspace carve (host+device identical) ----------------
struct WS {
  float *w0c, *Sw0, *w1c, *Sw1, *lnc, *Sln, *tmpK, *Krows, *Vrows,
        *Ybuf, *gyr, *Z0, *alv, *thv, *etv, *wBv, *wEv, *scal, *Qb, *Yr;
  u16 *xcb, *wqb, *wkvb, *w0b, *w1b, *w1tb, *Kb, *KT, *Hb, *Ht,
      *dYb, *dYtW, *dYtE, *dHtW, *dHtE, *Qbb, *Hrb;
};
__host__ __device__ inline WS mkws(char* base) {
  WS s; char* p = base + 256;
#define CF(nm, n) s.nm = (float*)p; p += (size_t)(n) * 4;
#define CU(nm, n) s.nm = (u16*)p;   p += (size_t)(n) * 2;
  CF(w0c, Ii*Dd) CF(Sw0, Ii*Dd) CF(w1c, Dd*Ii) CF(Sw1, Dd*Ii)
  CF(lnc, Dd) CF(Sln, Dd)
  CF(tmpK, (size_t)RowsAll*Dd) CF(Krows, (size_t)RowsAll*Dd) CF(Vrows, (size_t)RowsAll*Dd)
  CF(Ybuf, RowsC*Dd) CF(gyr, RowsC*Dd) CF(Z0, RowsC*Ii)
  CF(alv, Ss) CF(thv, Ss) CF(etv, Ss) CF(wBv, nCk*RowsC) CF(wEv, nCk*RowsC) CF(scal, nCk*4)
  CF(Qb, (size_t)RowsAll*Dd) CF(Yr, (size_t)RowsAll*Dd)
  CU(xcb, (size_t)RowsAll*Dd) CU(wqb, Dd*Dd) CU(wkvb, (size_t)Ii*Dd)
  CU(w0b, (size_t)Ii*Dd) CU(w1b, (size_t)Dd*Ii) CU(w1tb, (size_t)Ii*Dd)
  CU(Kb, (size_t)RowsAll*Dd) CU(KT, (size_t)RowsAll*Dd)
  CU(Hb, RowsC*Ii) CU(Ht, RowsC*Ii)
  CU(dYb, RowsC*Dd) CU(dYtW, RowsC*Dd) CU(dYtE, RowsC*Dd)
  CU(dHtW, RowsC*Ii) CU(dHtE, RowsC*Ii)
  CU(Qbb, (size_t)RowsAll*Dd) CU(Hrb, (size_t)RowsAll*Ii)
#undef CF
#undef CU
  return s;
}

// ---------------- 64x64 MFMA tile, BK-parametrized ----------------
// Swizzle: LDS slot j of row r holds global 16B-chunk j^(r&(CPR-1)).
// EPI: 0 C0=v | 1 KV split | 2 C0=v,Cb=bf(silu),CbT=bf(silu)^T
//      3 dh=v*silu'(Z): CbT=bf(dh*wB), CbT2=bf(dh*wE) | 4 Cb=bf(silu)
template<int BK, int EPI>
__device__ void tile64(
    u16* smA, u16* smB,
    const u16* __restrict__ A, const u16* __restrict__ Bt,
    int K, int N, int bm, int bn,
    float* C0, float* C1, u16* Cb, u16* CbT, u16* CbT2,
    const float* Z, const float* wB, const float* wE, int trM)
{
  constexpr int CPR = BK / 8;                 // 16B chunks per row
  constexpr int NISS = (64 * CPR) / 256;      // issues per buffer per thread
  const int tid = threadIdx.x;
  const int l = tid & 63, lr = l & 15, lq = l >> 4;
  const int w = tid >> 6, wr = w >> 1, wc = w & 1;

  f32x4 acc[2][2];
  #pragma unroll
  for (int i = 0; i < 2; ++i)
    #pragma unroll
    for (int j = 0; j < 2; ++j) acc[i][j] = f32x4{0.f, 0.f, 0.f, 0.f};

  for (int k0 = 0; k0 < K; k0 += BK) {
    #pragma unroll
    for (int i = 0; i < NISS; ++i) {
      int e = i * 256 + tid;
      int r = e / CPR, c = (e & (CPR - 1)) ^ (r & (CPR - 1));
      llds16(A  + (size_t)(bm + r) * K + k0 + c * 8, smA + e * 8);
      llds16(Bt + (size_t)(bn + r) * K + k0 + c * 8, smB + e * 8);
    }
    __syncthreads();
    #pragma unroll
    for (int kk = 0; kk < BK / 32; ++kk) {
      bf16x8 av[2], bv[2];
      #pragma unroll
      for (int m = 0; m < 2; ++m) {
        int r = wr * 32 + m * 16 + lr;
        int c = (kk * 4 + lq) ^ (r & (CPR - 1));
        av[m] = *reinterpret_cast<const bf16x8*>(&smA[r * BK + c * 8]);
      }
      #pragma unroll
      for (int n = 0; n < 2; ++n) {
        int r = wc * 32 + n * 16 + lr;
        int c = (kk * 4 + lq) ^ (r & (CPR - 1));
        bv[n] = *reinterpret_cast<const bf16x8*>(&smB[r * BK + c * 8]);
      }
      #pragma unroll
      for (int m = 0; m < 2; ++m)
        #pragma unroll
        for (int n = 0; n < 2; ++n)
          acc[m][n] = __builtin_amdgcn_mfma_f32_16x16x32_bf16(av[m], bv[n], acc[m][n], 0, 0, 0);
    }
    __syncthreads();
  }

  #pragma unroll
  for (int m = 0; m < 2; ++m) {
    int gr0 = bm + wr * 32 + m * 16 + lq * 4;
    float wbq[4], weq[4];
    if (EPI == 3) {
      #pragma unroll
      for (int q = 0; q < 4; ++q) { wbq[q] = wB[gr0 + q]; weq[q] = wE[gr0 + q]; }
    }
    #pragma unroll
    for (int n = 0; n < 2; ++n) {
      int gc = bn + wc * 32 + n * 16 + lr;
      ushort4 t1, t2;
      #pragma unroll
      for (int q = 0; q < 4; ++q) {
        float v = acc[m][n][q];
        size_t idx = (size_t)(gr0 + q) * N + gc;
        if (EPI == 0) {
          C0[idx] = v;
        } else if (EPI == 1) {
          if (gc < Dd) C0[(size_t)(gr0 + q) * Dd + gc] = v;
          else         C1[(size_t)(gr0 + q) * Dd + gc - Dd] = siluf_(v);
        } else if (EPI == 2) {
          C0[idx] = v;
          float h = siluf_(v);
          Cb[idx] = f2bf(h);
          ((u16*)&t1)[q] = f2bf(h);
        } else if (EPI == 3) {
          float z = Z[idx];
          float sg = 1.f / (1.f + expf(-z));
          float dh = v * sg * (1.f + z * (1.f - sg));
          ((u16*)&t1)[q] = f2bf(dh * wbq[q]);
          ((u16*)&t2)[q] = f2bf(dh * weq[q]);
        } else if (EPI == 4) {
          Cb[idx] = f2bf(siluf_(v));
        }
      }
      if (EPI == 2) *reinterpret_cast<ushort4*>(&CbT[(size_t)gc * trM + gr0]) = t1;
      if (EPI == 3) {
        *reinterpret_cast<ushort4*>(&CbT[(size_t)gc * trM + gr0]) = t1;
        *reinterpret_cast<ushort4*>(&CbT2[(size_t)gc * trM + gr0]) = t2;
      }
    }
  }
}

// ---------------- dual-weighted grad tile + fused param update ----------------
template<int BK, bool TR>
__device__ void gtile64(
    u16* smA, u16* smB, u16* smE,
    const u16* __restrict__ AW, const u16* __restrict__ AE,
    const u16* __restrict__ Bt,
    float* P, float* Sm, u16* Pb, u16* PbT, const float* scal,
    int M, int N, int K, int bm, int bn)
{
  constexpr int CPR = BK / 8;
  constexpr int NISS = (64 * CPR) / 256;
  const int tid = threadIdx.x;
  const int l = tid & 63, lr = l & 15, lq = l >> 4;
  const int w = tid >> 6, wr = w >> 1, wc = w & 1;

  f32x4 aM[2][2], aE[2][2];
  #pragma unroll
  for (int i = 0; i < 2; ++i)
    #pragma unroll
    for (int j = 0; j < 2; ++j) {
      aM[i][j] = f32x4{0.f, 0.f, 0.f, 0.f};
      aE[i][j] = f32x4{0.f, 0.f, 0.f, 0.f};
    }

  for (int k0 = 0; k0 < K; k0 += BK) {
    #pragma unroll
    for (int i = 0; i < NISS; ++i) {
      int e = i * 256 + tid;
      int r = e / CPR, c = (e & (CPR - 1)) ^ (r & (CPR - 1));
      llds16(AW + (size_t)(bm + r) * K + k0 + c * 8, smA + e * 8);
      llds16(AE + (size_t)(bm + r) * K + k0 + c * 8, smE + e * 8);
      llds16(Bt + (size_t)(bn + r) * K + k0 + c * 8, smB + e * 8);
    }
    __syncthreads();
    #pragma unroll
    for (int kk = 0; kk < BK / 32; ++kk) {
      bf16x8 awv[2], aev[2], bv[2];
      #pragma unroll
      for (int m = 0; m < 2; ++m) {
        int r = wr * 32 + m * 16 + lr;
        int c = (kk * 4 + lq) ^ (r & (CPR - 1));
        awv[m] = *reinterpret_cast<const bf16x8*>(&smA[r * BK + c * 8]);
        aev[m] = *reinterpret_cast<const bf16x8*>(&smE[r * BK + c * 8]);
      }
      #pragma unroll
      for (int n = 0; n < 2; ++n) {
        int r = wc * 32 + n * 16 + lr;
        int c = (kk * 4 + lq) ^ (r & (CPR - 1));
        bv[n] = *reinterpret_cast<const bf16x8*>(&smB[r * BK + c * 8]);
      }
      #pragma unroll
      for (int m = 0; m < 2; ++m)
        #pragma unroll
        for (int n = 0; n < 2; ++n) {
          aM[m][n] = __builtin_amdgcn_mfma_f32_16x16x32_bf16(awv[m], bv[n], aM[m][n], 0, 0, 0);
          aE[m][n] = __builtin_amdgcn_mfma_f32_16x16x32_bf16(aev[m], bv[n], aE[m][n], 0, 0, 0);
        }
    }
    __syncthreads();
  }

  float s0 = scal[0], s1 = scal[1], s2 = scal[2];
  #pragma unroll
  for (int m = 0; m < 2; ++m) {
    int gr0 = bm + wr * 32 + m * 16 + lq * 4;
    #pragma unroll
    for (int n = 0; n < 2; ++n) {
      int gc = bn + wc * 32 + n * 16 + lr;
      ushort4 t1;
      #pragma unroll
      for (int q = 0; q < 4; ++q) {
        size_t idx = (size_t)(gr0 + q) * N + gc;
        float p = P[idx], s = Sm[idx];
        float np = s0 * p + s1 * s - aM[m][n][q];
        float ns = s2 * s - aE[m][n][q];
        P[idx] = np; Sm[idx] = ns;
        Pb[idx] = f2bf(np);
        if (TR) ((u16*)&t1)[q] = f2bf(np);
      }
      if (TR) *reinterpret_cast<ushort4*>(&PbT[(size_t)gc * M + gr0]) = t1;
    }
  }
}

// ---------------- GEMM kernel wrappers ----------------
template<int BK, int EPI>
__global__ __launch_bounds__(256) void mgemm_k(
    const u16* __restrict__ A, const u16* __restrict__ Bt,
    float* C0, float* C1, u16* Cb, u16* CbT, u16* CbT2,
    const float* Z, const float* wB, const float* wE,
    int M, int N, int K, int trM)
{
  __shared__ __align__(16) u16 sm[2 * 64 * BK];
  tile64<BK, EPI>(sm, sm + 64 * BK, A, Bt, K, N,
                  blockIdx.y * 64, blockIdx.x * 64,
                  C0, C1, Cb, CbT, CbT2, Z, wB, wE, trM);
}

// 128x128-tile GEMM for retrieval (4 waves 2x2, 2x2 frags each of 64x64?) —
// use the proven 128-tile from round 3: FR=4, BK=64.
template<int EPI>
__global__ __launch_bounds__(256) void mgemm128_k(
    const u16* __restrict__ A, const u16* __restrict__ Bt,
    float* C0, u16* Cb, int M, int N, int K)
{
  constexpr int TS = 128, BK = 64;
  __shared__ __align__(16) u16 As[TS * BK];
  __shared__ __align__(16) u16 Bs[TS * BK];
  const int tid = threadIdx.x;
  const int l = tid & 63, lr = l & 15, lq = l >> 4;
  const int w = tid >> 6, wr = w >> 1, wc = w & 1;
  const int bm = blockIdx.y * TS, bn = blockIdx.x * TS;

  f32x4 acc[4][4];
  #pragma unroll
  for (int i = 0; i < 4; ++i)
    #pragma unroll
    for (int j = 0; j < 4; ++j) acc[i][j] = f32x4{0.f, 0.f, 0.f, 0.f};

  for (int k0 = 0; k0 < K; k0 += BK) {
    #pragma unroll
    for (int i = 0; i < 4; ++i) {
      int e = i * 256 + tid;
      int r = e >> 3, c = (e & 7) ^ (r & 7);
      llds16(A  + (size_t)(bm + r) * K + k0 + c * 8, As + e * 8);
      llds16(Bt + (size_t)(bn + r) * K + k0 + c * 8, Bs + e * 8);
    }
    __syncthreads();
    #pragma unroll
    for (int kk = 0; kk < 2; ++kk) {
      bf16x8 av[4], bv[4];
      #pragma unroll
      for (int m = 0; m < 4; ++m) {
        int r = wr * 64 + m * 16 + lr;
        int c = (kk * 4 + lq) ^ (r & 7);
        av[m] = *reinterpret_cast<const bf16x8*>(&As[r * BK + c * 8]);
      }
      #pragma unroll
      for (int n = 0; n < 4; ++n) {
        int r = wc * 64 + n * 16 + lr;
        int c = (kk * 4 + lq) ^ (r & 7);
        bv[n] = *reinterpret_cast<const bf16x8*>(&Bs[r * BK + c * 8]);
      }
      #pragma unroll
      for (int m = 0; m < 4; ++m)
        #pragma unroll
        for (int n = 0; n < 4; ++n)
          acc[m][n] = __builtin_amdgcn_mfma_f32_16x16x32_bf16(av[m], bv[n], acc[m][n], 0, 0, 0);
    }
    __syncthreads();
  }

  #pragma unroll
  for (int m = 0; m < 4; ++m) {
    int gr0 = bm + wr * 64 + m * 16 + lq * 4;
    #pragma unroll
    for (int n = 0; n < 4; ++n) {
      int gc = bn + wc * 64 + n * 16 + lr;
      #pragma unroll
      for (int q = 0; q < 4; ++q) {
        size_t idx = (size_t)(gr0 + q) * N + gc;
        float v = acc[m][n][q];
        if (EPI == 0) C0[idx] = v;
        else          Cb[idx] = f2bf(siluf_(v));
      }
    }
  }
}

// dH GEMM (64 blocks) + colsum/ln-update (blocks 64,65)
template<int BK>
__global__ __launch_bounds__(256) void dh_colsum_k(
    const u16* __restrict__ dYb, const u16* __restrict__ w1tb,
    u16* dHtW, u16* dHtE, const float* Z0,
    const float* wB, const float* wE,
    const float* gyr, float* lnc, float* Sln, const float* scal)
{
  __shared__ __align__(16) u16 sm[2 * 64 * BK];
  int j = blockIdx.x;
  if (j < 64) {
    int tm = j & 3, tn = j >> 2;
    tile64<BK, 3>(sm, sm + 64 * BK, dYb, w1tb, Dd, Ii, tm * 64, tn * 64,
                  nullptr, nullptr, nullptr, dHtW, dHtE, Z0, wB, wE, RowsC);
  } else {
    int d = (j - 64) * 256 + threadIdx.x;
    float sm2 = 0.f, se2 = 0.f;
    for (int r = 0; r < RowsC; ++r) {
      float vv = gyr[(size_t)r * Dd + d];
      sm2 += wB[r] * vv; se2 += wE[r] * vv;
    }
    float pp = lnc[d], sn = Sln[d];
    lnc[d] = scal[0] * pp + scal[1] * sn - sm2;
    Sln[d] = scal[2] * sn - se2;
  }
}

// combined dual grad GEMMs + fused param updates (256 blocks)
template<int BK>
__global__ __launch_bounds__(256) void g2_k(
    const u16* __restrict__ dYtW, const u16* __restrict__ dYtE,
    const u16* __restrict__ Ht,
    const u16* __restrict__ dHtW, const u16* __restrict__ dHtE,
    const u16* __restrict__ KTc,
    float* w1c, float* Sw1, u16* w1b, u16* w1tb,
    float* w0c, float* Sw0, u16* w0b,
    const float* scal)
{
  __shared__ __align__(16) u16 sm[3 * 64 * BK];
  int j = blockIdx.x;
  if (j < 128) {
    gtile64<BK, true>(sm, sm + 64 * BK, sm + 2 * 64 * BK, dYtW, dYtE, Ht,
                      w1c, Sw1, w1b, w1tb, scal, Dd, Ii, RowsC,
                      (j >> 4) * 64, (j & 15) * 64);
  } else {
    j -= 128;
    gtile64<BK, false>(sm, sm + 64 * BK, sm + 2 * 64 * BK, dHtW, dHtE, KTc,
                       w0c, Sw0, w0b, nullptr, scal, Ii, Dd, RowsC,
                       (j >> 3) * 64, (j & 7) * 64);
  }
}

// ---------------- init: all copies/converts/zeroes in one kernel ----------------
__global__ void init_k(const float* __restrict__ wq, const float* __restrict__ wkw,
                       const float* __restrict__ wvw, const float* __restrict__ mw0,
                       const float* __restrict__ mw1, const float* __restrict__ mln,
                       char* ws)
{
  WS S = mkws(ws);
  const int i0 = blockIdx.x * 256 + threadIdx.x;
  const int stride = gridDim.x * 256;
  for (int i = i0; i < (Dd * Dd) / 4; i += stride) {
    float4 v = ((const float4*)wq)[i];
    ushort4 o; o.x = f2bf(v.x); o.y = f2bf(v.y); o.z = f2bf(v.z); o.w = f2bf(v.w);
    ((ushort4*)S.wqb)[i] = o;
    v = ((const float4*)wkw)[i];
    o.x = f2bf(v.x); o.y = f2bf(v.y); o.z = f2bf(v.z); o.w = f2bf(v.w);
    ((ushort4*)S.wkvb)[i] = o;
    v = ((const float4*)wvw)[i];
    o.x = f2bf(v.x); o.y = f2bf(v.y); o.z = f2bf(v.z); o.w = f2bf(v.w);
    ((ushort4*)S.wkvb)[i + (Dd * Dd) / 4] = o;
  }
  for (int i = i0; i < (Ii * Dd) / 4; i += stride) {
    float4 z4; z4.x = z4.y = z4.z = z4.w = 0.f;
    float4 v = ((const float4*)mw0)[i];
    ((float4*)S.w0c)[i] = v; ((float4*)S.Sw0)[i] = z4;
    ushort4 o; o.x = f2bf(v.x); o.y = f2bf(v.y); o.z = f2bf(v.z); o.w = f2bf(v.w);
    ((ushort4*)S.w0b)[i] = o;
    v = ((const float4*)mw1)[i];
    ((float4*)S.w1c)[i] = v; ((float4*)S.Sw1)[i] = z4;
    o.x = f2bf(v.x); o.y = f2bf(v.y); o.z = f2bf(v.z); o.w = f2bf(v.w);
    ((ushort4*)S.w1b)[i] = o;
  }
  for (int i = i0; i < Dd; i += stride) { S.lnc[i] = mln[i]; S.Sln[i] = 0.f; }
}

// fp32 [R][C] -> bf16 [C][R]
__global__ __launch_bounds__(256) void transw_k(
    const float* __restrict__ src, int R, int C, u16* __restrict__ dst)
{
  __shared__ float t[64][65];
  const int bc = blockIdx.x * 64, br = blockIdx.y * 64;
  const int tid = threadIdx.x;
  #pragma unroll
  for (int i = 0; i < 16; ++i) {
    int e = tid + i * 256;
    int r = e >> 6, c = e & 63;
    t[r][c] = src[(size_t)(br + r) * C + bc + c];
  }
  __syncthreads();
  #pragma unroll
  for (int i = 0; i < 16; ++i) {
    int e = tid + i * 256;
    int rr = e >> 6, cc = e & 63;
    dst[(size_t)(bc + rr) * R + br + cc] = f2bf(t[cc][rr]);
  }
}

// prep: x -> chunk-ordered bf16; all-token gates
__global__ __launch_bounds__(256) void prep_k(
    const float* __restrict__ x,
    const float* __restrict__ aw, const float* __restrict__ ab,
    const float* __restrict__ tw, const float* __restrict__ tb,
    const float* __restrict__ ew, const float* __restrict__ eb,
    char* ws)
{
  WS S = mkws(ws);
  __shared__ float red[256];
  int s = blockIdx.x, tid = threadIdx.x;
  int ci = s >> 6, t = s & 63;
  float sa = 0.f, st = 0.f, se = 0.f;
  for (int b = 0; b < Bb; ++b) {
    const float* xr = x + ((size_t)b * Ss + s) * Dd;
    u16* dst = S.xcb + ((size_t)(ci * RowsC + b * Cc + t)) * Dd;
    for (int d = tid; d < Dd; d += 256) {
      float v = xr[d];
      dst[d] = f2bf(v);
      sa += v * aw[d]; st += v * tw[d]; se += v * ew[d];
    }
  }
  sa = block_reduce_sum(sa, red);
  st = block_reduce_sum(st, red);
  se = block_reduce_sum(se, red);
  if (tid == 0) {
    S.alv[s] = sigmoidf_(sa + Bb * ab[0]);
    S.thv[s] = sigmoidf_(st + Bb * tb[0]) * 0.01f;
    S.etv[s] = sigmoidf_(se + Bb * eb[0]);
  }
}

__global__ void gate_scan_all_k(char* ws)
{
  if (threadIdx.x != 0) return;
  WS S = mkws(ws);
  int ci = blockIdx.x;
  const float* alc = S.alv + ci * Cc;
  const float* etc_ = S.etv + ci * Cc;
  float beta[Cc], wb[Cc], ce[Cc], E[Cc], T[Cc];
  for (int i = 0; i < Cc; ++i) beta[i] = 1.f - alc[i];
  wb[Cc - 1] = 1.f;
  for (int m = Cc - 2; m >= 0; --m) wb[m] = wb[m + 1] * beta[m + 1];
  float bc_last = wb[0] * beta[0];
  float p = 1.f, A = 0.f;
  for (int m = 0; m < Cc; ++m) { p *= etc_[m]; ce[m] = p; A += wb[m] * ce[m]; }
  E[Cc - 1] = 1.f; T[Cc - 1] = 1.f;
  for (int n = Cc - 2; n >= 0; --n) {
    E[n] = E[n + 1] * etc_[n + 1];
    T[n] = wb[n] + etc_[n + 1] * T[n + 1];
  }
  for (int b = 0; b < Bb; ++b)
    for (int t = 0; t < Cc; ++t) {
      S.wBv[ci * RowsC + b * Cc + t] = T[t];
      S.wEv[ci * RowsC + b * Cc + t] = E[t];
    }
  S.scal[ci * 4 + 0] = bc_last; S.scal[ci * 4 + 1] = A; S.scal[ci * 4 + 2] = ce[Cc - 1];
}

// wave-per-row: out = rms(silu(in))*nw; TR builds per-chunk KT
template<bool TR>
__global__ __launch_bounds__(256) void silu_rms4_k(
    const float* __restrict__ in, float* __restrict__ out,
    u16* __restrict__ outb, u16* __restrict__ KT,
    const float* __restrict__ nw)
{
  __shared__ u16 lt[4][Dd];
  const int tid = threadIdx.x, w = tid >> 6, l = tid & 63;
  const int r0 = blockIdx.x * 4;
  const int row = r0 + w, d0 = l * 8;
  const float* ir = in + (size_t)row * Dd + d0;
  float v[8];
  *(float4*)&v[0] = *(const float4*)ir;
  *(float4*)&v[4] = *(const float4*)(ir + 4);
  float ss = 0.f;
  #pragma unroll
  for (int j = 0; j < 8; ++j) { v[j] = siluf_(v[j]); ss += v[j] * v[j]; }
  ss = wave_sum(ss);
  float rr = rsqrtf(ss / (float)Dd + EPS);
  float nv[8];
  *(float4*)&nv[0] = *(const float4*)(nw + d0);
  *(float4*)&nv[4] = *(const float4*)(nw + d0 + 4);
  float y[8]; u16x8 pb;
  #pragma unroll
  for (int j = 0; j < 8; ++j) { y[j] = v[j] * rr * nv[j]; pb[j] = f2bf(y[j]); }
  float* orow = out + (size_t)row * Dd + d0;
  *(float4*)orow       = *(float4*)&y[0];
  *(float4*)(orow + 4) = *(float4*)&y[4];
  *(u16x8*)(outb + (size_t)row * Dd + d0) = pb;
  if (TR) {
    int ci = r0 >> 8, rloc = r0 & 255;
    u16* KTc = KT + (size_t)ci * Dd * RowsC;
    #pragma unroll
    for (int j = 0; j < 8; ++j) lt[w][d0 + j] = pb[j];
    __syncthreads();
    for (int d = tid; d < Dd; d += 256) {
      ushort4 pk;
      pk.x = lt[0][d]; pk.y = lt[1][d]; pk.z = lt[2][d]; pk.w = lt[3][d];
      *reinterpret_cast<ushort4*>(&KTc[(size_t)d * RowsC + rloc]) = pk;
    }
  }
}

// wave-per-row loss backward
__global__ __launch_bounds__(256) void loss_back4_k(
    const float* __restrict__ Kr, const float* __restrict__ Vr,
    const float* __restrict__ Y, const float* __restrict__ lnc,
    const float* __restrict__ th, const float* __restrict__ wB,
    const float* __restrict__ wE,
    u16* __restrict__ dYb, u16* __restrict__ dYtW, u16* __restrict__ dYtE,
    float* __restrict__ gyr)
{
  __shared__ u16 lw[4][Dd];
  __shared__ u16 le[4][Dd];
  const int tid = threadIdx.x, w = tid >> 6, l = tid & 63;
  const int row = blockIdx.x * 4 + w, t = row & 63, d0 = l * 8;
  size_t base = (size_t)row * Dd + d0;

  float y[8], kk[8], vv[8], lv[8];
  *(float4*)&y[0]  = *(const float4*)(Y + base);
  *(float4*)&y[4]  = *(const float4*)(Y + base + 4);
  *(float4*)&kk[0] = *(const float4*)(Kr + base);
  *(float4*)&kk[4] = *(const float4*)(Kr + base + 4);
  *(float4*)&vv[0] = *(const float4*)(Vr + base);
  *(float4*)&vv[4] = *(const float4*)(Vr + base + 4);
  *(float4*)&lv[0] = *(const float4*)(lnc + d0);
  *(float4*)&lv[4] = *(const float4*)(lnc + d0 + 4);

  float ss = 0.f;
  #pragma unroll
  for (int q = 0; q < 8; ++q) ss += y[q] * y[q];
  ss = wave_sum(ss);
  float rr = rsqrtf(ss / (float)Dd + EPS);
  float c = 2.f * th[t] / (float)Dd;

  float g[8], s2 = 0.f;
  #pragma unroll
  for (int q = 0; q < 8; ++q) {
    g[q] = c * ((kk[q] + y[q] * rr * lv[q]) - vv[q]);
    s2 += g[q] * lv[q] * y[q];
  }
  s2 = wave_sum(s2);
  float coef = rr * rr * rr * s2 / (float)Dd;

  float wb = wB[row], we = wE[row];
  u16x8 pb; float gy[8];
  #pragma unroll
  for (int q = 0; q < 8; ++q) {
    float dv = rr * g[q] * lv[q] - coef * y[q];
    pb[q] = f2bf(dv);
    lw[w][d0 + q] = f2bf(dv * wb);
    le[w][d0 + q] = f2bf(dv * we);
    gy[q] = g[q] * y[q] * rr;
  }
  *(u16x8*)(dYb + base) = pb;
  *(float4*)(gyr + base)     = *(float4*)&gy[0];
  *(float4*)(gyr + base + 4) = *(float4*)&gy[4];

  __syncthreads();
  int r0 = blockIdx.x * 4;
  for (int d = tid; d < Dd; d += 256) {
    ushort4 pw, pe;
    pw.x = lw[0][d]; pw.y = lw[1][d]; pw.z = lw[2][d]; pw.w = lw[3][d];
    pe.x = le[0][d]; pe.y = le[1][d]; pe.z = le[2][d]; pe.w = le[3][d];
    *reinterpret_cast<ushort4*>(&dYtW[(size_t)d * RowsC + r0]) = pw;
    *reinterpret_cast<ushort4*>(&dYtE[(size_t)d * RowsC + r0]) = pe;
  }
}

// out[orig] = q + rms(y)*ln  (wave per row, permute back)
__global__ __launch_bounds__(256) void final4_k(
    const float* __restrict__ Q, const float* __restrict__ Y,
    const float* __restrict__ lnc, float* __restrict__ out)
{
  const int tid = threadIdx.x, w = tid >> 6, l = tid & 63;
  const int row = blockIdx.x * 4 + w;
  const int ci = row >> 8, wi = row & 255, b = wi >> 6, t = wi & 63;
  const int d0 = l * 8;
  const float* yr = Y + (size_t)row * Dd + d0;
  float y[8];
  *(float4*)&y[0] = *(const float4*)yr;
  *(float4*)&y[4] = *(const float4*)(yr + 4);
  float ss = 0.f;
  #pragma unroll
  for (int q = 0; q < 8; ++q) ss += y[q] * y[q];
  ss = wave_sum(ss);
  float rr = rsqrtf(ss / (float)Dd + EPS);
  const float* qb = Q + (size_t)row * Dd + d0;
  const float* lf = lnc + d0;
  float o[8];
  #pragma unroll
  for (int q = 0; q < 8; ++q) o[q] = qb[q] + y[q] * rr * lf[q];
  float* ob = out + ((size_t)b * Ss + ci * Cc + t) * Dd + d0;
  *(float4*)ob       = *(float4*)&o[0];
  *(float4*)(ob + 4) = *(float4*)&o[4];
}

} // namespace

extern "C" void kernel_launch(void* const* d_in, const int* in_sizes, int n_in,
                              void* d_out, int out_size, void* d_ws, size_t ws_size,
                              hipStream_t stream)
{
  const float* x   = (const float*)d_in[0];
  const float* wq  = (const float*)d_in[1];
  const float* wkw = (const float*)d_in[2];
  const float* wvw = (const float*)d_in[3];
  const float* qn  = (const float*)d_in[4];
  const float* kn  = (const float*)d_in[5];
  const float* aw  = (const float*)d_in[6];
  const float* ab  = (const float*)d_in[7];
  const float* tw  = (const float*)d_in[8];
  const float* tb  = (const float*)d_in[9];
  const float* ew  = (const float*)d_in[10];
  const float* eb  = (const float*)d_in[11];
  const float* mw0 = (const float*)d_in[12];
  const float* mw1 = (const float*)d_in[13];
  const float* mln = (const float*)d_in[14];
  float* out = (float*)d_out;
  char* ws = (char*)d_ws;
  WS S = mkws(ws);

  // ---- init + prep (param-independent, hoisted) ----
  init_k<<<1024, 256, 0, stream>>>(wq, wkw, wvw, mw0, mw1, mln, ws);
  transw_k<<<dim3(Ii / 64, Dd / 64), 256, 0, stream>>>(mw1, Dd, Ii, S.w1tb);
  prep_k<<<Ss, 256, 0, stream>>>(x, aw, ab, tw, tb, ew, eb, ws);
  gate_scan_all_k<<<nCk, 64, 0, stream>>>(ws);

  // all-chunk KV projection + K-norm (+KT); Q path hoisted too
  mgemm_k<128, 1><<<dim3(Ii / 64, RowsAll / 64), 256, 0, stream>>>(
      S.xcb, S.wkvb, S.tmpK, S.Vrows, nullptr, nullptr, nullptr,
      nullptr, nullptr, nullptr, RowsAll, Ii, Dd, 0);
  silu_rms4_k<true><<<RowsAll / 4, 256, 0, stream>>>(S.tmpK, S.Krows, S.Kb, S.KT, kn);
  mgemm128_k<0><<<dim3(Dd / 128, RowsAll / 128), 256, 0, stream>>>(
      S.xcb, S.wqb, S.Yr, nullptr, RowsAll, Dd, Dd);
  silu_rms4_k<false><<<RowsAll / 4, 256, 0, stream>>>(S.Yr, S.Qb, S.Qbb, nullptr, qn);

  // ---- sequential chunk loop: 5 launches per chunk ----
  for (int ci = 0; ci < nCk; ++ci) {
    const u16* Kbc = S.Kb + (size_t)ci * RowsC * Dd;
    const u16* KTc = S.KT + (size_t)ci * Dd * RowsC;
    const float* Krc = S.Krows + (size_t)ci * RowsC * Dd;
    const float* Vrc = S.Vrows + (size_t)ci * RowsC * Dd;
    const float* scc = S.scal + ci * 4;
    const float* wBc = S.wBv + ci * RowsC;
    const float* wEc = S.wEv + ci * RowsC;
    const float* thc = S.thv + ci * Cc;

    mgemm_k<128, 2><<<dim3(Ii / 64, RowsC / 64), 256, 0, stream>>>(
        Kbc, S.w0b, S.Z0, nullptr, S.Hb, S.Ht, nullptr,
        nullptr, nullptr, nullptr, RowsC, Ii, Dd, RowsC);
    mgemm_k<128, 0><<<dim3(Dd / 64, RowsC / 64), 256, 0, stream>>>(
        S.Hb, S.w1b, S.Ybuf, nullptr, nullptr, nullptr, nullptr,
        nullptr, nullptr, nullptr, RowsC, Dd, Ii, 0);
    loss_back4_k<<<RowsC / 4, 256, 0, stream>>>(
        Krc, Vrc, S.Ybuf, S.lnc, thc, wBc, wEc, S.dYb, S.dYtW, S.dYtE, S.gyr);
    dh_colsum_k<128><<<66, 256, 0, stream>>>(
        S.dYb, S.w1tb, S.dHtW, S.dHtE, S.Z0, wBc, wEc, S.gyr, S.lnc, S.Sln, scc);
    g2_k<128><<<256, 256, 0, stream>>>(
        S.dYtW, S.dYtE, S.Ht, S.dHtW, S.dHtE, KTc,
        S.w1c, S.Sw1, S.w1b, S.w1tb, S.w0c, S.Sw0, S.w0b, scc);
  }

  // ---- retrieval through final memory ----
  mgemm128_k<4><<<dim3(Ii / 128, RowsAll / 128), 256, 0, stream>>>(
      S.Qbb, S.w0b, nullptr, S.Hrb, RowsAll, Ii, Dd);
  mgemm128_k<0><<<dim3(Dd / 128, RowsAll / 128), 256, 0, stream>>>(
      S.Hrb, S.w1b, S.Yr, nullptr, RowsAll, Dd, Ii);
  final4_k<<<RowsAll / 4, 256, 0, stream>>>(S.Qb, S.Yr, S.lnc, out);
}

// Round 6
// 429.607 us; speedup vs baseline: 8.5601x; 1.0987x over previous
//
#include <hip/hip_runtime.h>
#include <math.h>

#define EPS 1e-6f

namespace {

typedef unsigned short u16;
typedef unsigned int u32;
typedef __bf16 bf16x8 __attribute__((ext_vector_type(8)));
typedef float f32x4 __attribute__((ext_vector_type(4)));
typedef u16 u16x8 __attribute__((ext_vector_type(8)));

constexpr int Bb = 4, Ss = 512, Dd = 512, Ii = 1024, Cc = 64;
constexpr int nCk = 8, RowsC = 256, RowsAll = 2048;

__device__ __forceinline__ float sigmoidf_(float x) { return 1.f / (1.f + expf(-x)); }
__device__ __forceinline__ float siluf_(float x)    { return x / (1.f + expf(-x)); }

__device__ __forceinline__ u16 f2bf(float f) {
  u32 u = __float_as_uint(f);
  u32 r = u + 0x7fffu + ((u >> 16) & 1u);
  return (u16)(r >> 16);
}

__device__ __forceinline__ void llds16(const u16* g, u16* l) {
  __builtin_amdgcn_global_load_lds((__attribute__((address_space(1))) void*)g,
                                   (__attribute__((address_space(3))) void*)l,
                                   16, 0, 0);
}

__device__ __forceinline__ void drain_barrier() {
  asm volatile("s_waitcnt vmcnt(0)" ::: "memory");
  __builtin_amdgcn_s_barrier();
}

__device__ __forceinline__ float wave_sum(float v) {
  #pragma unroll
  for (int m = 32; m > 0; m >>= 1) v += __shfl_xor(v, m, 64);
  return v;
}

__device__ __forceinline__ float block_reduce_sum(float v, float* red) {
  int tid = threadIdx.x;
  red[tid] = v; __syncthreads();
  for (int s = 128; s > 0; s >>= 1) {
    if (tid < s) red[tid] += red[tid + s];
    __syncthreads();
  }
  float r = red[0]; __syncthreads();
  return r;
}

// ---------------- workspace carve (host+device identical) ----------------
struct WS {
  float *w0c, *Sw0, *w1c, *Sw1, *lnc, *Sln, *tmpK, *Krows, *Vrows,
        *Ybuf, *gyr, *Z0, *alv, *thv, *etv, *wBv, *wEv, *scal, *Qb, *Yr;
  u16 *xcb, *wqb, *wkvb, *w0b, *w1b, *w1tb, *Kb, *KT, *Hb, *Ht,
      *dYb, *dYtW, *dYtE, *dHtW, *dHtE, *Qbb, *Hrb;
};
__host__ __device__ inline WS mkws(char* base) {
  WS s; char* p = base + 256;
#define CF(nm, n) s.nm = (float*)p; p += (size_t)(n) * 4;
#define CU(nm, n) s.nm = (u16*)p;   p += (size_t)(n) * 2;
  CF(w0c, Ii*Dd) CF(Sw0, Ii*Dd) CF(w1c, Dd*Ii) CF(Sw1, Dd*Ii)
  CF(lnc, Dd) CF(Sln, Dd)
  CF(tmpK, (size_t)RowsAll*Dd) CF(Krows, (size_t)RowsAll*Dd) CF(Vrows, (size_t)RowsAll*Dd)
  CF(Ybuf, RowsC*Dd) CF(gyr, RowsC*Dd) CF(Z0, RowsC*Ii)
  CF(alv, Ss) CF(thv, Ss) CF(etv, Ss) CF(wBv, nCk*RowsC) CF(wEv, nCk*RowsC) CF(scal, nCk*4)
  CF(Qb, (size_t)RowsAll*Dd) CF(Yr, (size_t)RowsAll*Dd)
  CU(xcb, (size_t)RowsAll*Dd) CU(wqb, Dd*Dd) CU(wkvb, (size_t)Ii*Dd)
  CU(w0b, (size_t)Ii*Dd) CU(w1b, (size_t)Dd*Ii) CU(w1tb, (size_t)Ii*Dd)
  CU(Kb, (size_t)RowsAll*Dd) CU(KT, (size_t)RowsAll*Dd)
  CU(Hb, RowsC*Ii) CU(Ht, RowsC*Ii)
  CU(dYb, RowsC*Dd) CU(dYtW, RowsC*Dd) CU(dYtE, RowsC*Dd)
  CU(dHtW, RowsC*Ii) CU(dHtE, RowsC*Ii)
  CU(Qbb, (size_t)RowsAll*Dd) CU(Hrb, (size_t)RowsAll*Ii)
#undef CF
#undef CU
  return s;
}

// ---------------- 64x64 MFMA tile, BK-param, 2-phase double-buffered ----------
// smA/smB each hold 2 buffers of 64*BK.
// EPI: 0 C0=v | 1 KV split | 2 C0=v,Cb=bf(silu),CbT=bf(silu)^T
//      3 dh=v*silu'(Z): CbT=bf(dh*wB), CbT2=bf(dh*wE) | 4 Cb=bf(silu)
template<int BK, int EPI>
__device__ void tile64(
    u16* smA, u16* smB,
    const u16* __restrict__ A, const u16* __restrict__ Bt,
    int K, int N, int bm, int bn,
    float* C0, float* C1, u16* Cb, u16* CbT, u16* CbT2,
    const float* Z, const float* wB, const float* wE, int trM)
{
  constexpr int CPR = BK / 8;
  constexpr int NISS = (64 * CPR) / 256;
  constexpr int BUF = 64 * BK;
  const int tid = threadIdx.x;
  const int l = tid & 63, lr = l & 15, lq = l >> 4;
  const int w = tid >> 6, wr = w >> 1, wc = w & 1;

  f32x4 acc[2][2];
  #pragma unroll
  for (int i = 0; i < 2; ++i)
    #pragma unroll
    for (int j = 0; j < 2; ++j) acc[i][j] = f32x4{0.f, 0.f, 0.f, 0.f};

  auto stage = [&](int k0, int buf) {
    u16* dA = smA + buf * BUF;
    u16* dB = smB + buf * BUF;
    #pragma unroll
    for (int i = 0; i < NISS; ++i) {
      int e = i * 256 + tid;
      int r = e / CPR, c = (e & (CPR - 1)) ^ (r & (CPR - 1));
      llds16(A  + (size_t)(bm + r) * K + k0 + c * 8, dA + e * 8);
      llds16(Bt + (size_t)(bn + r) * K + k0 + c * 8, dB + e * 8);
    }
  };

  stage(0, 0);
  drain_barrier();
  const int nt = K / BK;
  int cur = 0;
  for (int t = 0; t < nt; ++t) {
    if (t + 1 < nt) stage((t + 1) * BK, cur ^ 1);
    const u16* sA = smA + cur * BUF;
    const u16* sB = smB + cur * BUF;
    #pragma unroll
    for (int kk = 0; kk < BK / 32; ++kk) {
      bf16x8 av[2], bv[2];
      #pragma unroll
      for (int m = 0; m < 2; ++m) {
        int r = wr * 32 + m * 16 + lr;
        int c = (kk * 4 + lq) ^ (r & (CPR - 1));
        av[m] = *reinterpret_cast<const bf16x8*>(&sA[r * BK + c * 8]);
      }
      #pragma unroll
      for (int n = 0; n < 2; ++n) {
        int r = wc * 32 + n * 16 + lr;
        int c = (kk * 4 + lq) ^ (r & (CPR - 1));
        bv[n] = *reinterpret_cast<const bf16x8*>(&sB[r * BK + c * 8]);
      }
      #pragma unroll
      for (int m = 0; m < 2; ++m)
        #pragma unroll
        for (int n = 0; n < 2; ++n)
          acc[m][n] = __builtin_amdgcn_mfma_f32_16x16x32_bf16(av[m], bv[n], acc[m][n], 0, 0, 0);
    }
    drain_barrier();
    cur ^= 1;
  }

  #pragma unroll
  for (int m = 0; m < 2; ++m) {
    int gr0 = bm + wr * 32 + m * 16 + lq * 4;
    float wbq[4], weq[4];
    if (EPI == 3) {
      #pragma unroll
      for (int q = 0; q < 4; ++q) { wbq[q] = wB[gr0 + q]; weq[q] = wE[gr0 + q]; }
    }
    #pragma unroll
    for (int n = 0; n < 2; ++n) {
      int gc = bn + wc * 32 + n * 16 + lr;
      ushort4 t1, t2;
      #pragma unroll
      for (int q = 0; q < 4; ++q) {
        float v = acc[m][n][q];
        size_t idx = (size_t)(gr0 + q) * N + gc;
        if (EPI == 0) {
          C0[idx] = v;
        } else if (EPI == 1) {
          if (gc < Dd) C0[(size_t)(gr0 + q) * Dd + gc] = v;
          else         C1[(size_t)(gr0 + q) * Dd + gc - Dd] = siluf_(v);
        } else if (EPI == 2) {
          C0[idx] = v;
          float h = siluf_(v);
          Cb[idx] = f2bf(h);
          ((u16*)&t1)[q] = f2bf(h);
        } else if (EPI == 3) {
          float z = Z[idx];
          float sg = 1.f / (1.f + expf(-z));
          float dh = v * sg * (1.f + z * (1.f - sg));
          ((u16*)&t1)[q] = f2bf(dh * wbq[q]);
          ((u16*)&t2)[q] = f2bf(dh * weq[q]);
        } else if (EPI == 4) {
          Cb[idx] = f2bf(siluf_(v));
        }
      }
      if (EPI == 2) *reinterpret_cast<ushort4*>(&CbT[(size_t)gc * trM + gr0]) = t1;
      if (EPI == 3) {
        *reinterpret_cast<ushort4*>(&CbT[(size_t)gc * trM + gr0]) = t1;
        *reinterpret_cast<ushort4*>(&CbT2[(size_t)gc * trM + gr0]) = t2;
      }
    }
  }
}

// ------------- dual-weighted grad tile + fused param update (dbuf) -----------
template<int BK, bool TR>
__device__ void gtile64(
    u16* smA, u16* smB, u16* smE,
    const u16* __restrict__ AW, const u16* __restrict__ AE,
    const u16* __restrict__ Bt,
    float* P, float* Sm, u16* Pb, u16* PbT, const float* scal,
    int M, int N, int K, int bm, int bn)
{
  constexpr int CPR = BK / 8;
  constexpr int NISS = (64 * CPR) / 256;
  constexpr int BUF = 64 * BK;
  const int tid = threadIdx.x;
  const int l = tid & 63, lr = l & 15, lq = l >> 4;
  const int w = tid >> 6, wr = w >> 1, wc = w & 1;

  f32x4 aM[2][2], aE[2][2];
  #pragma unroll
  for (int i = 0; i < 2; ++i)
    #pragma unroll
    for (int j = 0; j < 2; ++j) {
      aM[i][j] = f32x4{0.f, 0.f, 0.f, 0.f};
      aE[i][j] = f32x4{0.f, 0.f, 0.f, 0.f};
    }

  auto stage = [&](int k0, int buf) {
    u16* dA = smA + buf * BUF;
    u16* dE = smE + buf * BUF;
    u16* dB = smB + buf * BUF;
    #pragma unroll
    for (int i = 0; i < NISS; ++i) {
      int e = i * 256 + tid;
      int r = e / CPR, c = (e & (CPR - 1)) ^ (r & (CPR - 1));
      llds16(AW + (size_t)(bm + r) * K + k0 + c * 8, dA + e * 8);
      llds16(AE + (size_t)(bm + r) * K + k0 + c * 8, dE + e * 8);
      llds16(Bt + (size_t)(bn + r) * K + k0 + c * 8, dB + e * 8);
    }
  };

  stage(0, 0);
  drain_barrier();
  const int nt = K / BK;
  int cur = 0;
  for (int t = 0; t < nt; ++t) {
    if (t + 1 < nt) stage((t + 1) * BK, cur ^ 1);
    const u16* sA = smA + cur * BUF;
    const u16* sE = smE + cur * BUF;
    const u16* sB = smB + cur * BUF;
    #pragma unroll
    for (int kk = 0; kk < BK / 32; ++kk) {
      bf16x8 awv[2], aev[2], bv[2];
      #pragma unroll
      for (int m = 0; m < 2; ++m) {
        int r = wr * 32 + m * 16 + lr;
        int c = (kk * 4 + lq) ^ (r & (CPR - 1));
        awv[m] = *reinterpret_cast<const bf16x8*>(&sA[r * BK + c * 8]);
        aev[m] = *reinterpret_cast<const bf16x8*>(&sE[r * BK + c * 8]);
      }
      #pragma unroll
      for (int n = 0; n < 2; ++n) {
        int r = wc * 32 + n * 16 + lr;
        int c = (kk * 4 + lq) ^ (r & (CPR - 1));
        bv[n] = *reinterpret_cast<const bf16x8*>(&sB[r * BK + c * 8]);
      }
      #pragma unroll
      for (int m = 0; m < 2; ++m)
        #pragma unroll
        for (int n = 0; n < 2; ++n) {
          aM[m][n] = __builtin_amdgcn_mfma_f32_16x16x32_bf16(awv[m], bv[n], aM[m][n], 0, 0, 0);
          aE[m][n] = __builtin_amdgcn_mfma_f32_16x16x32_bf16(aev[m], bv[n], aE[m][n], 0, 0, 0);
        }
    }
    drain_barrier();
    cur ^= 1;
  }

  float s0 = scal[0], s1 = scal[1], s2 = scal[2];
  #pragma unroll
  for (int m = 0; m < 2; ++m) {
    int gr0 = bm + wr * 32 + m * 16 + lq * 4;
    #pragma unroll
    for (int n = 0; n < 2; ++n) {
      int gc = bn + wc * 32 + n * 16 + lr;
      ushort4 t1;
      #pragma unroll
      for (int q = 0; q < 4; ++q) {
        size_t idx = (size_t)(gr0 + q) * N + gc;
        float p = P[idx], s = Sm[idx];
        float np = s0 * p + s1 * s - aM[m][n][q];
        float ns = s2 * s - aE[m][n][q];
        P[idx] = np; Sm[idx] = ns;
        Pb[idx] = f2bf(np);
        if (TR) ((u16*)&t1)[q] = f2bf(np);
      }
      if (TR) *reinterpret_cast<ushort4*>(&PbT[(size_t)gc * M + gr0]) = t1;
    }
  }
}

// ---------------- GEMM kernel wrappers ----------------
template<int BK, int EPI>
__global__ __launch_bounds__(256) void mgemm_k(
    const u16* __restrict__ A, const u16* __restrict__ Bt,
    float* C0, float* C1, u16* Cb, u16* CbT, u16* CbT2,
    const float* Z, const float* wB, const float* wE,
    int M, int N, int K, int trM)
{
  __shared__ __align__(16) u16 sm[4 * 64 * BK];
  tile64<BK, EPI>(sm, sm + 2 * 64 * BK, A, Bt, K, N,
                  blockIdx.y * 64, blockIdx.x * 64,
                  C0, C1, Cb, CbT, CbT2, Z, wB, wE, trM);
}

// 128x128-tile GEMM (2-phase dbuf)
template<int EPI>
__global__ __launch_bounds__(256) void mgemm128_k(
    const u16* __restrict__ A, const u16* __restrict__ Bt,
    float* C0, u16* Cb, int M, int N, int K)
{
  constexpr int TS = 128, BK = 64;
  constexpr int BUF = TS * BK;
  __shared__ __align__(16) u16 As[2 * BUF];
  __shared__ __align__(16) u16 Bs[2 * BUF];
  const int tid = threadIdx.x;
  const int l = tid & 63, lr = l & 15, lq = l >> 4;
  const int w = tid >> 6, wr = w >> 1, wc = w & 1;
  const int bm = blockIdx.y * TS, bn = blockIdx.x * TS;

  f32x4 acc[4][4];
  #pragma unroll
  for (int i = 0; i < 4; ++i)
    #pragma unroll
    for (int j = 0; j < 4; ++j) acc[i][j] = f32x4{0.f, 0.f, 0.f, 0.f};

  auto stage = [&](int k0, int buf) {
    u16* dA = As + buf * BUF;
    u16* dB = Bs + buf * BUF;
    #pragma unroll
    for (int i = 0; i < 4; ++i) {
      int e = i * 256 + tid;
      int r = e >> 3, c = (e & 7) ^ (r & 7);
      llds16(A  + (size_t)(bm + r) * K + k0 + c * 8, dA + e * 8);
      llds16(Bt + (size_t)(bn + r) * K + k0 + c * 8, dB + e * 8);
    }
  };

  stage(0, 0);
  drain_barrier();
  const int nt = K / BK;
  int cur = 0;
  for (int t = 0; t < nt; ++t) {
    if (t + 1 < nt) stage((t + 1) * BK, cur ^ 1);
    const u16* sA = As + cur * BUF;
    const u16* sB = Bs + cur * BUF;
    #pragma unroll
    for (int kk = 0; kk < 2; ++kk) {
      bf16x8 av[4], bv[4];
      #pragma unroll
      for (int m = 0; m < 4; ++m) {
        int r = wr * 64 + m * 16 + lr;
        int c = (kk * 4 + lq) ^ (r & 7);
        av[m] = *reinterpret_cast<const bf16x8*>(&sA[r * BK + c * 8]);
      }
      #pragma unroll
      for (int n = 0; n < 4; ++n) {
        int r = wc * 64 + n * 16 + lr;
        int c = (kk * 4 + lq) ^ (r & 7);
        bv[n] = *reinterpret_cast<const bf16x8*>(&sB[r * BK + c * 8]);
      }
      #pragma unroll
      for (int m = 0; m < 4; ++m)
        #pragma unroll
        for (int n = 0; n < 4; ++n)
          acc[m][n] = __builtin_amdgcn_mfma_f32_16x16x32_bf16(av[m], bv[n], acc[m][n], 0, 0, 0);
    }
    drain_barrier();
    cur ^= 1;
  }

  #pragma unroll
  for (int m = 0; m < 4; ++m) {
    int gr0 = bm + wr * 64 + m * 16 + lq * 4;
    #pragma unroll
    for (int n = 0; n < 4; ++n) {
      int gc = bn + wc * 64 + n * 16 + lr;
      #pragma unroll
      for (int q = 0; q < 4; ++q) {
        size_t idx = (size_t)(gr0 + q) * N + gc;
        float v = acc[m][n][q];
        if (EPI == 0) C0[idx] = v;
        else          Cb[idx] = f2bf(siluf_(v));
      }
    }
  }
}

// dH GEMM (64 blocks) + colsum/ln-update (blocks 64,65)
template<int BK>
__global__ __launch_bounds__(256) void dh_colsum_k(
    const u16* __restrict__ dYb, const u16* __restrict__ w1tb,
    u16* dHtW, u16* dHtE, const float* Z0,
    const float* wB, const float* wE,
    const float* gyr, float* lnc, float* Sln, const float* scal)
{
  __shared__ __align__(16) u16 sm[4 * 64 * BK];
  int j = blockIdx.x;
  if (j < 64) {
    int tm = j & 3, tn = j >> 2;
    tile64<BK, 3>(sm, sm + 2 * 64 * BK, dYb, w1tb, Dd, Ii, tm * 64, tn * 64,
                  nullptr, nullptr, nullptr, dHtW, dHtE, Z0, wB, wE, RowsC);
  } else {
    int d = (j - 64) * 256 + threadIdx.x;
    float sm2 = 0.f, se2 = 0.f;
    for (int r = 0; r < RowsC; ++r) {
      float vv = gyr[(size_t)r * Dd + d];
      sm2 += wB[r] * vv; se2 += wE[r] * vv;
    }
    float pp = lnc[d], sn = Sln[d];
    lnc[d] = scal[0] * pp + scal[1] * sn - sm2;
    Sln[d] = scal[2] * sn - se2;
  }
}

// combined dual grad GEMMs + fused param updates (256 blocks)
template<int BK>
__global__ __launch_bounds__(256) void g2_k(
    const u16* __restrict__ dYtW, const u16* __restrict__ dYtE,
    const u16* __restrict__ Ht,
    const u16* __restrict__ dHtW, const u16* __restrict__ dHtE,
    const u16* __restrict__ KTc,
    float* w1c, float* Sw1, u16* w1b, u16* w1tb,
    float* w0c, float* Sw0, u16* w0b,
    const float* scal)
{
  __shared__ __align__(16) u16 sm[6 * 64 * BK];
  int j = blockIdx.x;
  if (j < 128) {
    gtile64<BK, true>(sm, sm + 2 * 64 * BK, sm + 4 * 64 * BK, dYtW, dYtE, Ht,
                      w1c, Sw1, w1b, w1tb, scal, Dd, Ii, RowsC,
                      (j >> 4) * 64, (j & 15) * 64);
  } else {
    j -= 128;
    gtile64<BK, false>(sm, sm + 2 * 64 * BK, sm + 4 * 64 * BK, dHtW, dHtE, KTc,
                       w0c, Sw0, w0b, nullptr, scal, Ii, Dd, RowsC,
                       (j >> 3) * 64, (j & 7) * 64);
  }
}

// ---------------- init: copies/converts/zeroes + w1^T (one kernel) ----------
__global__ __launch_bounds__(256) void init_k(
    const float* __restrict__ wq, const float* __restrict__ wkw,
    const float* __restrict__ wvw, const float* __restrict__ mw0,
    const float* __restrict__ mw1, const float* __restrict__ mln,
    char* ws)
{
  WS S = mkws(ws);
  __shared__ float t[64][65];
  if (blockIdx.x < 128) {
    // transpose tile of mw1 [Dd][Ii] -> w1tb [Ii][Dd]
    int j = blockIdx.x;
    int br = (j & 7) * 64, bc = (j >> 3) * 64;
    const int tid = threadIdx.x;
    #pragma unroll
    for (int i = 0; i < 16; ++i) {
      int e = tid + i * 256;
      int r = e >> 6, c = e & 63;
      t[r][c] = mw1[(size_t)(br + r) * Ii + bc + c];
    }
    __syncthreads();
    #pragma unroll
    for (int i = 0; i < 16; ++i) {
      int e = tid + i * 256;
      int rr = e >> 6, cc = e & 63;
      S.w1tb[(size_t)(bc + rr) * Dd + br + cc] = f2bf(t[cc][rr]);
    }
    return;
  }
  const int i0 = (blockIdx.x - 128) * 256 + threadIdx.x;
  const int stride = (gridDim.x - 128) * 256;
  for (int i = i0; i < (Dd * Dd) / 4; i += stride) {
    float4 v = ((const float4*)wq)[i];
    ushort4 o; o.x = f2bf(v.x); o.y = f2bf(v.y); o.z = f2bf(v.z); o.w = f2bf(v.w);
    ((ushort4*)S.wqb)[i] = o;
    v = ((const float4*)wkw)[i];
    o.x = f2bf(v.x); o.y = f2bf(v.y); o.z = f2bf(v.z); o.w = f2bf(v.w);
    ((ushort4*)S.wkvb)[i] = o;
    v = ((const float4*)wvw)[i];
    o.x = f2bf(v.x); o.y = f2bf(v.y); o.z = f2bf(v.z); o.w = f2bf(v.w);
    ((ushort4*)S.wkvb)[i + (Dd * Dd) / 4] = o;
  }
  for (int i = i0; i < (Ii * Dd) / 4; i += stride) {
    float4 z4; z4.x = z4.y = z4.z = z4.w = 0.f;
    float4 v = ((const float4*)mw0)[i];
    ((float4*)S.w0c)[i] = v; ((float4*)S.Sw0)[i] = z4;
    ushort4 o; o.x = f2bf(v.x); o.y = f2bf(v.y); o.z = f2bf(v.z); o.w = f2bf(v.w);
    ((ushort4*)S.w0b)[i] = o;
    v = ((const float4*)mw1)[i];
    ((float4*)S.w1c)[i] = v; ((float4*)S.Sw1)[i] = z4;
    o.x = f2bf(v.x); o.y = f2bf(v.y); o.z = f2bf(v.z); o.w = f2bf(v.w);
    ((ushort4*)S.w1b)[i] = o;
  }
  for (int i = i0; i < Dd; i += stride) { S.lnc[i] = mln[i]; S.Sln[i] = 0.f; }
}

// prep: x -> chunk-ordered bf16; all-token gates
__global__ __launch_bounds__(256) void prep_k(
    const float* __restrict__ x,
    const float* __restrict__ aw, const float* __restrict__ ab,
    const float* __restrict__ tw, const float* __restrict__ tb,
    const float* __restrict__ ew, const float* __restrict__ eb,
    char* ws)
{
  WS S = mkws(ws);
  __shared__ float red[256];
  int s = blockIdx.x, tid = threadIdx.x;
  int ci = s >> 6, t = s & 63;
  float sa = 0.f, st = 0.f, se = 0.f;
  for (int b = 0; b < Bb; ++b) {
    const float* xr = x + ((size_t)b * Ss + s) * Dd;
    u16* dst = S.xcb + ((size_t)(ci * RowsC + b * Cc + t)) * Dd;
    for (int d = tid; d < Dd; d += 256) {
      float v = xr[d];
      dst[d] = f2bf(v);
      sa += v * aw[d]; st += v * tw[d]; se += v * ew[d];
    }
  }
  sa = block_reduce_sum(sa, red);
  st = block_reduce_sum(st, red);
  se = block_reduce_sum(se, red);
  if (tid == 0) {
    S.alv[s] = sigmoidf_(sa + Bb * ab[0]);
    S.thv[s] = sigmoidf_(st + Bb * tb[0]) * 0.01f;
    S.etv[s] = sigmoidf_(se + Bb * eb[0]);
  }
}

__global__ void gate_scan_all_k(char* ws)
{
  if (threadIdx.x != 0) return;
  WS S = mkws(ws);
  int ci = blockIdx.x;
  const float* alc = S.alv + ci * Cc;
  const float* etc_ = S.etv + ci * Cc;
  float beta[Cc], wb[Cc], ce[Cc], E[Cc], T[Cc];
  for (int i = 0; i < Cc; ++i) beta[i] = 1.f - alc[i];
  wb[Cc - 1] = 1.f;
  for (int m = Cc - 2; m >= 0; --m) wb[m] = wb[m + 1] * beta[m + 1];
  float bc_last = wb[0] * beta[0];
  float p = 1.f, A = 0.f;
  for (int m = 0; m < Cc; ++m) { p *= etc_[m]; ce[m] = p; A += wb[m] * ce[m]; }
  E[Cc - 1] = 1.f; T[Cc - 1] = 1.f;
  for (int n = Cc - 2; n >= 0; --n) {
    E[n] = E[n + 1] * etc_[n + 1];
    T[n] = wb[n] + etc_[n + 1] * T[n + 1];
  }
  for (int b = 0; b < Bb; ++b)
    for (int t = 0; t < Cc; ++t) {
      S.wBv[ci * RowsC + b * Cc + t] = T[t];
      S.wEv[ci * RowsC + b * Cc + t] = E[t];
    }
  S.scal[ci * 4 + 0] = bc_last; S.scal[ci * 4 + 1] = A; S.scal[ci * 4 + 2] = ce[Cc - 1];
}

// wave-per-row: out = rms(silu(in))*nw; TR builds per-chunk KT
template<bool TR>
__global__ __launch_bounds__(256) void silu_rms4_k(
    const float* __restrict__ in, float* __restrict__ out,
    u16* __restrict__ outb, u16* __restrict__ KT,
    const float* __restrict__ nw)
{
  __shared__ u16 lt[4][Dd];
  const int tid = threadIdx.x, w = tid >> 6, l = tid & 63;
  const int r0 = blockIdx.x * 4;
  const int row = r0 + w, d0 = l * 8;
  const float* ir = in + (size_t)row * Dd + d0;
  float v[8];
  *(float4*)&v[0] = *(const float4*)ir;
  *(float4*)&v[4] = *(const float4*)(ir + 4);
  float ss = 0.f;
  #pragma unroll
  for (int j = 0; j < 8; ++j) { v[j] = siluf_(v[j]); ss += v[j] * v[j]; }
  ss = wave_sum(ss);
  float rr = rsqrtf(ss / (float)Dd + EPS);
  float nv[8];
  *(float4*)&nv[0] = *(const float4*)(nw + d0);
  *(float4*)&nv[4] = *(const float4*)(nw + d0 + 4);
  float y[8]; u16x8 pb;
  #pragma unroll
  for (int j = 0; j < 8; ++j) { y[j] = v[j] * rr * nv[j]; pb[j] = f2bf(y[j]); }
  float* orow = out + (size_t)row * Dd + d0;
  *(float4*)orow       = *(float4*)&y[0];
  *(float4*)(orow + 4) = *(float4*)&y[4];
  *(u16x8*)(outb + (size_t)row * Dd + d0) = pb;
  if (TR) {
    int ci = r0 >> 8, rloc = r0 & 255;
    u16* KTc = KT + (size_t)ci * Dd * RowsC;
    #pragma unroll
    for (int j = 0; j < 8; ++j) lt[w][d0 + j] = pb[j];
    __syncthreads();
    for (int d = tid; d < Dd; d += 256) {
      ushort4 pk;
      pk.x = lt[0][d]; pk.y = lt[1][d]; pk.z = lt[2][d]; pk.w = lt[3][d];
      *reinterpret_cast<ushort4*>(&KTc[(size_t)d * RowsC + rloc]) = pk;
    }
  }
}

// wave-per-row loss backward
__global__ __launch_bounds__(256) void loss_back4_k(
    const float* __restrict__ Kr, const float* __restrict__ Vr,
    const float* __restrict__ Y, const float* __restrict__ lnc,
    const float* __restrict__ th, const float* __restrict__ wB,
    const float* __restrict__ wE,
    u16* __restrict__ dYb, u16* __restrict__ dYtW, u16* __restrict__ dYtE,
    float* __restrict__ gyr)
{
  __shared__ u16 lw[4][Dd];
  __shared__ u16 le[4][Dd];
  const int tid = threadIdx.x, w = tid >> 6, l = tid & 63;
  const int row = blockIdx.x * 4 + w, t = row & 63, d0 = l * 8;
  size_t base = (size_t)row * Dd + d0;

  float y[8], kk[8], vv[8], lv[8];
  *(float4*)&y[0]  = *(const float4*)(Y + base);
  *(float4*)&y[4]  = *(const float4*)(Y + base + 4);
  *(float4*)&kk[0] = *(const float4*)(Kr + base);
  *(float4*)&kk[4] = *(const float4*)(Kr + base + 4);
  *(float4*)&vv[0] = *(const float4*)(Vr + base);
  *(float4*)&vv[4] = *(const float4*)(Vr + base + 4);
  *(float4*)&lv[0] = *(const float4*)(lnc + d0);
  *(float4*)&lv[4] = *(const float4*)(lnc + d0 + 4);

  float ss = 0.f;
  #pragma unroll
  for (int q = 0; q < 8; ++q) ss += y[q] * y[q];
  ss = wave_sum(ss);
  float rr = rsqrtf(ss / (float)Dd + EPS);
  float c = 2.f * th[t] / (float)Dd;

  float g[8], s2 = 0.f;
  #pragma unroll
  for (int q = 0; q < 8; ++q) {
    g[q] = c * ((kk[q] + y[q] * rr * lv[q]) - vv[q]);
    s2 += g[q] * lv[q] * y[q];
  }
  s2 = wave_sum(s2);
  float coef = rr * rr * rr * s2 / (float)Dd;

  float wb = wB[row], we = wE[row];
  u16x8 pb; float gy[8];
  #pragma unroll
  for (int q = 0; q < 8; ++q) {
    float dv = rr * g[q] * lv[q] - coef * y[q];
    pb[q] = f2bf(dv);
    lw[w][d0 + q] = f2bf(dv * wb);
    le[w][d0 + q] = f2bf(dv * we);
    gy[q] = g[q] * y[q] * rr;
  }
  *(u16x8*)(dYb + base) = pb;
  *(float4*)(gyr + base)     = *(float4*)&gy[0];
  *(float4*)(gyr + base + 4) = *(float4*)&gy[4];

  __syncthreads();
  int r0 = blockIdx.x * 4;
  for (int d = tid; d < Dd; d += 256) {
    ushort4 pw, pe;
    pw.x = lw[0][d]; pw.y = lw[1][d]; pw.z = lw[2][d]; pw.w = lw[3][d];
    pe.x = le[0][d]; pe.y = le[1][d]; pe.z = le[2][d]; pe.w = le[3][d];
    *reinterpret_cast<ushort4*>(&dYtW[(size_t)d * RowsC + r0]) = pw;
    *reinterpret_cast<ushort4*>(&dYtE[(size_t)d * RowsC + r0]) = pe;
  }
}

// out[orig] = q + rms(y)*ln  (wave per row, permute back)
__global__ __launch_bounds__(256) void final4_k(
    const float* __restrict__ Q, const float* __restrict__ Y,
    const float* __restrict__ lnc, float* __restrict__ out)
{
  const int tid = threadIdx.x, w = tid >> 6, l = tid & 63;
  const int row = blockIdx.x * 4 + w;
  const int ci = row >> 8, wi = row & 255, b = wi >> 6, t = wi & 63;
  const int d0 = l * 8;
  const float* yr = Y + (size_t)row * Dd + d0;
  float y[8];
  *(float4*)&y[0] = *(const float4*)yr;
  *(float4*)&y[4] = *(const float4*)(yr + 4);
  float ss = 0.f;
  #pragma unroll
  for (int q = 0; q < 8; ++q) ss += y[q] * y[q];
  ss = wave_sum(ss);
  float rr = rsqrtf(ss / (float)Dd + EPS);
  const float* qb = Q + (size_t)row * Dd + d0;
  const float* lf = lnc + d0;
  float o[8];
  #pragma unroll
  for (int q = 0; q < 8; ++q) o[q] = qb[q] + y[q] * rr * lf[q];
  float* ob = out + ((size_t)b * Ss + ci * Cc + t) * Dd + d0;
  *(float4*)ob       = *(float4*)&o[0];
  *(float4*)(ob + 4) = *(float4*)&o[4];
}

} // namespace

extern "C" void kernel_launch(void* const* d_in, const int* in_sizes, int n_in,
                              void* d_out, int out_size, void* d_ws, size_t ws_size,
                              hipStream_t stream)
{
  const float* x   = (const float*)d_in[0];
  const float* wq  = (const float*)d_in[1];
  const float* wkw = (const float*)d_in[2];
  const float* wvw = (const float*)d_in[3];
  const float* qn  = (const float*)d_in[4];
  const float* kn  = (const float*)d_in[5];
  const float* aw  = (const float*)d_in[6];
  const float* ab  = (const float*)d_in[7];
  const float* tw  = (const float*)d_in[8];
  const float* tb  = (const float*)d_in[9];
  const float* ew  = (const float*)d_in[10];
  const float* eb  = (const float*)d_in[11];
  const float* mw0 = (const float*)d_in[12];
  const float* mw1 = (const float*)d_in[13];
  const float* mln = (const float*)d_in[14];
  float* out = (float*)d_out;
  char* ws = (char*)d_ws;
  WS S = mkws(ws);

  // ---- init + prep (param-independent, hoisted) ----
  init_k<<<1024 + 128, 256, 0, stream>>>(wq, wkw, wvw, mw0, mw1, mln, ws);
  prep_k<<<Ss, 256, 0, stream>>>(x, aw, ab, tw, tb, ew, eb, ws);
  gate_scan_all_k<<<nCk, 64, 0, stream>>>(ws);

  // all-chunk KV projection + K-norm (+KT); Q path hoisted too
  mgemm_k<128, 1><<<dim3(Ii / 64, RowsAll / 64), 256, 0, stream>>>(
      S.xcb, S.wkvb, S.tmpK, S.Vrows, nullptr, nullptr, nullptr,
      nullptr, nullptr, nullptr, RowsAll, Ii, Dd, 0);
  silu_rms4_k<true><<<RowsAll / 4, 256, 0, stream>>>(S.tmpK, S.Krows, S.Kb, S.KT, kn);
  mgemm128_k<0><<<dim3(Dd / 128, RowsAll / 128), 256, 0, stream>>>(
      S.xcb, S.wqb, S.Yr, nullptr, RowsAll, Dd, Dd);
  silu_rms4_k<false><<<RowsAll / 4, 256, 0, stream>>>(S.Yr, S.Qb, S.Qbb, nullptr, qn);

  // ---- sequential chunk loop: 5 launches per chunk ----
  for (int ci = 0; ci < nCk; ++ci) {
    const u16* Kbc = S.Kb + (size_t)ci * RowsC * Dd;
    const u16* KTc = S.KT + (size_t)ci * Dd * RowsC;
    const float* Krc = S.Krows + (size_t)ci * RowsC * Dd;
    const float* Vrc = S.Vrows + (size_t)ci * RowsC * Dd;
    const float* scc = S.scal + ci * 4;
    const float* wBc = S.wBv + ci * RowsC;
    const float* wEc = S.wEv + ci * RowsC;
    const float* thc = S.thv + ci * Cc;

    mgemm_k<128, 2><<<dim3(Ii / 64, RowsC / 64), 256, 0, stream>>>(
        Kbc, S.w0b, S.Z0, nullptr, S.Hb, S.Ht, nullptr,
        nullptr, nullptr, nullptr, RowsC, Ii, Dd, RowsC);
    mgemm_k<128, 0><<<dim3(Dd / 64, RowsC / 64), 256, 0, stream>>>(
        S.Hb, S.w1b, S.Ybuf, nullptr, nullptr, nullptr, nullptr,
        nullptr, nullptr, nullptr, RowsC, Dd, Ii, 0);
    loss_back4_k<<<RowsC / 4, 256, 0, stream>>>(
        Krc, Vrc, S.Ybuf, S.lnc, thc, wBc, wEc, S.dYb, S.dYtW, S.dYtE, S.gyr);
    dh_colsum_k<128><<<66, 256, 0, stream>>>(
        S.dYb, S.w1tb, S.dHtW, S.dHtE, S.Z0, wBc, wEc, S.gyr, S.lnc, S.Sln, scc);
    g2_k<128><<<256, 256, 0, stream>>>(
        S.dYtW, S.dYtE, S.Ht, S.dHtW, S.dHtE, KTc,
        S.w1c, S.Sw1, S.w1b, S.w1tb, S.w0c, S.Sw0, S.w0b, scc);
  }

  // ---- retrieval through final memory ----
  mgemm128_k<4><<<dim3(Ii / 128, RowsAll / 128), 256, 0, stream>>>(
      S.Qbb, S.w0b, nullptr, S.Hrb, RowsAll, Ii, Dd);
  mgemm128_k<0><<<dim3(Dd / 128, RowsAll / 128), 256, 0, stream>>>(
      S.Hrb, S.w1b, S.Yr, nullptr, RowsAll, Dd, Ii);
  final4_k<<<RowsAll / 4, 256, 0, stream>>>(S.Qb, S.Yr, S.lnc, out);
}

// Round 7
// 393.701 us; speedup vs baseline: 9.3408x; 1.0912x over previous
//
#include <hip/hip_runtime.h>
#include <math.h>

#define EPS 1e-6f

namespace {

typedef unsigned short u16;
typedef unsigned int u32;
typedef __bf16 bf16x8 __attribute__((ext_vector_type(8)));
typedef float f32x4 __attribute__((ext_vector_type(4)));
typedef u16 u16x8 __attribute__((ext_vector_type(8)));

constexpr int Bb = 4, Ss = 512, Dd = 512, Ii = 1024, Cc = 64;
constexpr int nCk = 8, RowsC = 256, RowsAll = 2048;

__device__ __forceinline__ float sigmoidf_(float x) { return 1.f / (1.f + expf(-x)); }
__device__ __forceinline__ float siluf_(float x)    { return x / (1.f + expf(-x)); }

__device__ __forceinline__ u16 f2bf(float f) {
  u32 u = __float_as_uint(f);
  u32 r = u + 0x7fffu + ((u >> 16) & 1u);
  return (u16)(r >> 16);
}
__device__ __forceinline__ float bf2f(u16 u) {
  return __uint_as_float(((u32)u) << 16);
}

__device__ __forceinline__ void llds16(const u16* g, u16* l) {
  __builtin_amdgcn_global_load_lds((__attribute__((address_space(1))) void*)g,
                                   (__attribute__((address_space(3))) void*)l,
                                   16, 0, 0);
}

__device__ __forceinline__ void drain_barrier() {
  asm volatile("s_waitcnt vmcnt(0)" ::: "memory");
  __builtin_amdgcn_s_barrier();
}

__device__ __forceinline__ float wave_sum(float v) {
  #pragma unroll
  for (int m = 32; m > 0; m >>= 1) v += __shfl_xor(v, m, 64);
  return v;
}

__device__ __forceinline__ float block_reduce_sum(float v, float* red) {
  int tid = threadIdx.x;
  red[tid] = v; __syncthreads();
  for (int s = 128; s > 0; s >>= 1) {
    if (tid < s) red[tid] += red[tid + s];
    __syncthreads();
  }
  float r = red[0]; __syncthreads();
  return r;
}

// ---------------- workspace carve ----------------
struct WS {
  float *w0c, *Sw0, *w1c, *Sw1, *lnc, *Sln, *tmpK, *Krows, *Vrows,
        *Ybuf, *gyr, *alv, *thv, *etv, *wBv, *wEv, *scal, *Qb, *Yr;
  u16 *xcb, *wkvqb, *w0b, *w1b, *w1tb, *Kb, *KT, *Hb, *Ht, *dZb,
      *dYb, *dYtW, *dYtE, *dHtW, *dHtE, *Qbb, *Hrb;
};
__host__ __device__ inline WS mkws(char* base) {
  WS s; char* p = base + 256;
#define CF(nm, n) s.nm = (float*)p; p += (size_t)(n) * 4;
#define CU(nm, n) s.nm = (u16*)p;   p += (size_t)(n) * 2;
  CF(w0c, Ii*Dd) CF(Sw0, Ii*Dd) CF(w1c, Dd*Ii) CF(Sw1, Dd*Ii)
  CF(lnc, Dd) CF(Sln, Dd)
  CF(tmpK, (size_t)RowsAll*Dd) CF(Krows, (size_t)RowsAll*Dd) CF(Vrows, (size_t)RowsAll*Dd)
  CF(Ybuf, RowsC*Dd) CF(gyr, RowsC*Dd)
  CF(alv, Ss) CF(thv, Ss) CF(etv, Ss) CF(wBv, nCk*RowsC) CF(wEv, nCk*RowsC) CF(scal, nCk*4)
  CF(Qb, (size_t)RowsAll*Dd) CF(Yr, (size_t)RowsAll*Dd)
  CU(xcb, (size_t)RowsAll*Dd) CU(wkvqb, (size_t)3*Dd*Dd)
  CU(w0b, (size_t)Ii*Dd) CU(w1b, (size_t)2*Dd*Ii) CU(w1tb, (size_t)2*Ii*Dd)
  CU(Kb, (size_t)RowsAll*Dd) CU(KT, (size_t)RowsAll*Dd)
  CU(Hb, RowsC*Ii) CU(Ht, RowsC*Ii) CU(dZb, RowsC*Ii)
  CU(dYb, RowsC*Dd) CU(dYtW, RowsC*Dd) CU(dYtE, RowsC*Dd)
  CU(dHtW, RowsC*Ii) CU(dHtE, RowsC*Ii)
  CU(Qbb, (size_t)RowsAll*Dd) CU(Hrb, (size_t)RowsAll*Ii)
#undef CF
#undef CU
  return s;
}

// ---------------- 64x64 MFMA tile, BK/NBUF-param ----------------
// NBUF=2: 2-phase double-buffered.  NBUF=1: single-shot (K must == BK).
// EPI: 0 C0=v
//      1 KVQ split: gc<512->C0=v | gc<1024->C1=silu(v) | else C2=v (all ld=Dd)
//      2 Cb=bf(silu(v)), CbT=bf(silu)^T, CbT2=bf(silu'(v)) row-major
//      3 dh=v*bf2f(Zb): CbT=bf(dh*wB)^T, CbT2=bf(dh*wE)^T
//      4 Cb=bf(silu(v))
template<int BK, int NBUF, int EPI>
__device__ void tile64(
    u16* smA, u16* smB,
    const u16* __restrict__ A, const u16* __restrict__ Bt,
    int K, int N, int bm, int bn,
    float* C0, float* C1, float* C2,
    u16* Cb, u16* CbT, u16* CbT2,
    const u16* Zb, const float* wB, const float* wE, int trM)
{
  constexpr int CPR = BK / 8;
  constexpr int NISS = (64 * CPR) / 256;
  constexpr int BUF = 64 * BK;
  const int tid = threadIdx.x;
  const int l = tid & 63, lr = l & 15, lq = l >> 4;
  const int w = tid >> 6, wr = w >> 1, wc = w & 1;

  f32x4 acc[2][2];
  #pragma unroll
  for (int i = 0; i < 2; ++i)
    #pragma unroll
    for (int j = 0; j < 2; ++j) acc[i][j] = f32x4{0.f, 0.f, 0.f, 0.f};

  auto stage = [&](int k0, int buf) {
    u16* dA = smA + buf * BUF;
    u16* dB = smB + buf * BUF;
    #pragma unroll
    for (int i = 0; i < NISS; ++i) {
      int e = i * 256 + tid;
      int r = e / CPR, c = (e & (CPR - 1)) ^ (r & (CPR - 1));
      llds16(A  + (size_t)(bm + r) * K + k0 + c * 8, dA + e * 8);
      llds16(Bt + (size_t)(bn + r) * K + k0 + c * 8, dB + e * 8);
    }
  };

  stage(0, 0);
  drain_barrier();
  const int nt = K / BK;
  int cur = 0;
  for (int t = 0; t < nt; ++t) {
    if (t + 1 < nt) stage((t + 1) * BK, (cur ^ 1) & (NBUF - 1));
    const u16* sA = smA + cur * BUF;
    const u16* sB = smB + cur * BUF;
    #pragma unroll
    for (int kk = 0; kk < BK / 32; ++kk) {
      bf16x8 av[2], bv[2];
      #pragma unroll
      for (int m = 0; m < 2; ++m) {
        int r = wr * 32 + m * 16 + lr;
        int c = (kk * 4 + lq) ^ (r & (CPR - 1));
        av[m] = *reinterpret_cast<const bf16x8*>(&sA[r * BK + c * 8]);
      }
      #pragma unroll
      for (int n = 0; n < 2; ++n) {
        int r = wc * 32 + n * 16 + lr;
        int c = (kk * 4 + lq) ^ (r & (CPR - 1));
        bv[n] = *reinterpret_cast<const bf16x8*>(&sB[r * BK + c * 8]);
      }
      #pragma unroll
      for (int m = 0; m < 2; ++m)
        #pragma unroll
        for (int n = 0; n < 2; ++n)
          acc[m][n] = __builtin_amdgcn_mfma_f32_16x16x32_bf16(av[m], bv[n], acc[m][n], 0, 0, 0);
    }
    drain_barrier();
    cur = (cur ^ 1) & (NBUF - 1);
  }

  #pragma unroll
  for (int m = 0; m < 2; ++m) {
    int gr0 = bm + wr * 32 + m * 16 + lq * 4;
    float wbq[4], weq[4];
    if (EPI == 3) {
      #pragma unroll
      for (int q = 0; q < 4; ++q) { wbq[q] = wB[gr0 + q]; weq[q] = wE[gr0 + q]; }
    }
    #pragma unroll
    for (int n = 0; n < 2; ++n) {
      int gc = bn + wc * 32 + n * 16 + lr;
      ushort4 t1, t2;
      #pragma unroll
      for (int q = 0; q < 4; ++q) {
        float v = acc[m][n][q];
        size_t idx = (size_t)(gr0 + q) * N + gc;
        if (EPI == 0) {
          C0[idx] = v;
        } else if (EPI == 1) {
          size_t rb = (size_t)(gr0 + q) * Dd;
          if (gc < Dd)            C0[rb + gc] = v;
          else if (gc < 2 * Dd)   C1[rb + gc - Dd] = siluf_(v);
          else                    C2[rb + gc - 2 * Dd] = v;
        } else if (EPI == 2) {
          float sg = 1.f / (1.f + expf(-v));
          float h = v * sg;
          float ds = sg * (1.f + v * (1.f - sg));
          Cb[idx] = f2bf(h);
          CbT2[idx] = f2bf(ds);
          ((u16*)&t1)[q] = f2bf(h);
        } else if (EPI == 3) {
          float dh = v * bf2f(Zb[idx]);
          ((u16*)&t1)[q] = f2bf(dh * wbq[q]);
          ((u16*)&t2)[q] = f2bf(dh * weq[q]);
        } else if (EPI == 4) {
          Cb[idx] = f2bf(siluf_(v));
        }
      }
      if (EPI == 2) *reinterpret_cast<ushort4*>(&CbT[(size_t)gc * trM + gr0]) = t1;
      if (EPI == 3) {
        *reinterpret_cast<ushort4*>(&CbT[(size_t)gc * trM + gr0]) = t1;
        *reinterpret_cast<ushort4*>(&CbT2[(size_t)gc * trM + gr0]) = t2;
      }
    }
  }
}

// ------------- dual-weighted grad tile + fused param update -----------
template<int BK, int NBUF, bool TR>
__device__ void gtile64(
    u16* smA, u16* smB, u16* smE,
    const u16* __restrict__ AW, const u16* __restrict__ AE,
    const u16* __restrict__ Bt,
    float* P, float* Sm, u16* Pb, u16* PbT, const float* scal,
    int M, int N, int K, int bm, int bn)
{
  constexpr int CPR = BK / 8;
  constexpr int NISS = (64 * CPR) / 256;
  constexpr int BUF = 64 * BK;
  const int tid = threadIdx.x;
  const int l = tid & 63, lr = l & 15, lq = l >> 4;
  const int w = tid >> 6, wr = w >> 1, wc = w & 1;

  f32x4 aM[2][2], aE[2][2];
  #pragma unroll
  for (int i = 0; i < 2; ++i)
    #pragma unroll
    for (int j = 0; j < 2; ++j) {
      aM[i][j] = f32x4{0.f, 0.f, 0.f, 0.f};
      aE[i][j] = f32x4{0.f, 0.f, 0.f, 0.f};
    }

  auto stage = [&](int k0, int buf) {
    u16* dA = smA + buf * BUF;
    u16* dE = smE + buf * BUF;
    u16* dB = smB + buf * BUF;
    #pragma unroll
    for (int i = 0; i < NISS; ++i) {
      int e = i * 256 + tid;
      int r = e / CPR, c = (e & (CPR - 1)) ^ (r & (CPR - 1));
      llds16(AW + (size_t)(bm + r) * K + k0 + c * 8, dA + e * 8);
      llds16(AE + (size_t)(bm + r) * K + k0 + c * 8, dE + e * 8);
      llds16(Bt + (size_t)(bn + r) * K + k0 + c * 8, dB + e * 8);
    }
  };

  stage(0, 0);
  drain_barrier();
  const int nt = K / BK;
  int cur = 0;
  for (int t = 0; t < nt; ++t) {
    if (t + 1 < nt) stage((t + 1) * BK, (cur ^ 1) & (NBUF - 1));
    const u16* sA = smA + cur * BUF;
    const u16* sE = smE + cur * BUF;
    const u16* sB = smB + cur * BUF;
    #pragma unroll
    for (int kk = 0; kk < BK / 32; ++kk) {
      bf16x8 awv[2], aev[2], bv[2];
      #pragma unroll
      for (int m = 0; m < 2; ++m) {
        int r = wr * 32 + m * 16 + lr;
        int c = (kk * 4 + lq) ^ (r & (CPR - 1));
        awv[m] = *reinterpret_cast<const bf16x8*>(&sA[r * BK + c * 8]);
        aev[m] = *reinterpret_cast<const bf16x8*>(&sE[r * BK + c * 8]);
      }
      #pragma unroll
      for (int n = 0; n < 2; ++n) {
        int r = wc * 32 + n * 16 + lr;
        int c = (kk * 4 + lq) ^ (r & (CPR - 1));
        bv[n] = *reinterpret_cast<const bf16x8*>(&sB[r * BK + c * 8]);
      }
      #pragma unroll
      for (int m = 0; m < 2; ++m)
        #pragma unroll
        for (int n = 0; n < 2; ++n) {
          aM[m][n] = __builtin_amdgcn_mfma_f32_16x16x32_bf16(awv[m], bv[n], aM[m][n], 0, 0, 0);
          aE[m][n] = __builtin_amdgcn_mfma_f32_16x16x32_bf16(aev[m], bv[n], aE[m][n], 0, 0, 0);
        }
    }
    drain_barrier();
    cur = (cur ^ 1) & (NBUF - 1);
  }

  float s0 = scal[0], s1 = scal[1], s2 = scal[2];
  #pragma unroll
  for (int m = 0; m < 2; ++m) {
    int gr0 = bm + wr * 32 + m * 16 + lq * 4;
    #pragma unroll
    for (int n = 0; n < 2; ++n) {
      int gc = bn + wc * 32 + n * 16 + lr;
      ushort4 t1;
      #pragma unroll
      for (int q = 0; q < 4; ++q) {
        size_t idx = (size_t)(gr0 + q) * N + gc;
        float p = P[idx], s = Sm[idx];
        float np = s0 * p + s1 * s - aM[m][n][q];
        float ns = s2 * s - aE[m][n][q];
        P[idx] = np; Sm[idx] = ns;
        Pb[idx] = f2bf(np);
        if (TR) ((u16*)&t1)[q] = f2bf(np);
      }
      if (TR) *reinterpret_cast<ushort4*>(&PbT[(size_t)gc * M + gr0]) = t1;
    }
  }
}

// ---------------- kernels ----------------

// Z0 GEMM: Hb=bf(silu), Ht=transposed, dZb=bf(silu')   [grid (16,4)]
__global__ __launch_bounds__(256) void z0_k(
    const u16* __restrict__ A, const u16* __restrict__ Bt,
    u16* Hb, u16* Ht, u16* dZb)
{
  __shared__ __align__(16) u16 sm[4 * 64 * 256];
  tile64<256, 2, 2>(sm, sm + 2 * 64 * 256, A, Bt, Dd, Ii,
                    blockIdx.y * 64, blockIdx.x * 64,
                    nullptr, nullptr, nullptr, Hb, Ht, dZb,
                    nullptr, nullptr, nullptr, RowsC);
}

// Y GEMM [grid (8,4)]
__global__ __launch_bounds__(256) void y_k(
    const u16* __restrict__ A, const u16* __restrict__ Bt, float* C0)
{
  __shared__ __align__(16) u16 sm[4 * 64 * 256];
  tile64<256, 2, 0>(sm, sm + 2 * 64 * 256, A, Bt, Ii, Dd,
                    blockIdx.y * 64, blockIdx.x * 64,
                    C0, nullptr, nullptr, nullptr, nullptr, nullptr,
                    nullptr, nullptr, nullptr, 0);
}

// S4: dH GEMM (blk 0-63) + colsum/ln (blk 64-65) + w1 grad+update (blk 66-193)
__global__ __launch_bounds__(256) void s4_k(
    const u16* __restrict__ dYb, const u16* __restrict__ w1t_cur,
    const u16* __restrict__ dZb, u16* dHtW, u16* dHtE,
    const float* __restrict__ gyr, float* lnc, float* Sln,
    const u16* __restrict__ dYtW, const u16* __restrict__ dYtE,
    const u16* __restrict__ Ht,
    float* w1c, float* Sw1, u16* w1b_new, u16* w1t_new,
    const float* wB, const float* wE, const float* scal)
{
  __shared__ __align__(16) u16 sm[4 * 64 * 256];
  int j = blockIdx.x;
  if (j < 64) {
    int tm = j & 3, tn = j >> 2;
    tile64<256, 2, 3>(sm, sm + 2 * 64 * 256, dYb, w1t_cur, Dd, Ii,
                      tm * 64, tn * 64,
                      nullptr, nullptr, nullptr, nullptr, dHtW, dHtE,
                      dZb, wB, wE, RowsC);
  } else if (j < 66) {
    int d = (j - 64) * 256 + threadIdx.x;
    float sm2 = 0.f, se2 = 0.f;
    for (int r = 0; r < RowsC; ++r) {
      float vv = gyr[(size_t)r * Dd + d];
      sm2 += wB[r] * vv; se2 += wE[r] * vv;
    }
    float pp = lnc[d], sn = Sln[d];
    lnc[d] = scal[0] * pp + scal[1] * sn - sm2;
    Sln[d] = scal[2] * sn - se2;
  } else {
    int q = j - 66;                       // 128 tiles: M=Dd(8) x N=Ii(16)
    gtile64<256, 1, true>(sm, sm + 64 * 256, sm + 2 * 64 * 256,
                          dYtW, dYtE, Ht, w1c, Sw1, w1b_new, w1t_new,
                          scal, Dd, Ii, RowsC, (q >> 4) * 64, (q & 15) * 64);
  }
}

// w0 grad + update [grid 128]
__global__ __launch_bounds__(256) void g2b_k(
    const u16* __restrict__ dHtW, const u16* __restrict__ dHtE,
    const u16* __restrict__ KTc,
    float* w0c, float* Sw0, u16* w0b, const float* scal)
{
  __shared__ __align__(16) u16 sm[3 * 64 * 256];
  int j = blockIdx.x;                     // M=Ii(16) x N=Dd(8)
  gtile64<256, 1, false>(sm, sm + 64 * 256, sm + 2 * 64 * 256,
                         dHtW, dHtE, KTc, w0c, Sw0, w0b, nullptr,
                         scal, Ii, Dd, RowsC, (j >> 3) * 64, (j & 7) * 64);
}

// KVQ GEMM (blk 0-767) + per-chunk gate scans (blk 768-775)
__global__ __launch_bounds__(256) void kvq_k(
    const u16* __restrict__ xcb, const u16* __restrict__ wkvqb,
    float* tmpK, float* Vrows, float* Yq, char* ws)
{
  __shared__ __align__(16) u16 sm[4 * 64 * 128];
  int j = blockIdx.x;
  if (j < 768) {
    int tn = j % 24, tm = j / 24;
    tile64<128, 2, 1>(sm, sm + 2 * 64 * 128, xcb, wkvqb, Dd, 3 * Dd,
                      tm * 64, tn * 64,
                      tmpK, Vrows, Yq, nullptr, nullptr, nullptr,
                      nullptr, nullptr, nullptr, 0);
    return;
  }
  if (threadIdx.x != 0) return;
  WS S = mkws(ws);
  int ci = j - 768;
  const float* alc = S.alv + ci * Cc;
  const float* etc_ = S.etv + ci * Cc;
  float beta[Cc], wb[Cc], ce[Cc], E[Cc], T[Cc];
  for (int i = 0; i < Cc; ++i) beta[i] = 1.f - alc[i];
  wb[Cc - 1] = 1.f;
  for (int m = Cc - 2; m >= 0; --m) wb[m] = wb[m + 1] * beta[m + 1];
  float bc_last = wb[0] * beta[0];
  float p = 1.f, A = 0.f;
  for (int m = 0; m < Cc; ++m) { p *= etc_[m]; ce[m] = p; A += wb[m] * ce[m]; }
  E[Cc - 1] = 1.f; T[Cc - 1] = 1.f;
  for (int n = Cc - 2; n >= 0; --n) {
    E[n] = E[n + 1] * etc_[n + 1];
    T[n] = wb[n] + etc_[n + 1] * T[n + 1];
  }
  for (int b = 0; b < Bb; ++b)
    for (int t = 0; t < Cc; ++t) {
      S.wBv[ci * RowsC + b * Cc + t] = T[t];
      S.wEv[ci * RowsC + b * Cc + t] = E[t];
    }
  S.scal[ci * 4 + 0] = bc_last; S.scal[ci * 4 + 1] = A; S.scal[ci * 4 + 2] = ce[Cc - 1];
}

// 128x128-tile GEMM (2-phase dbuf) for retrieval
template<int EPI>
__global__ __launch_bounds__(256) void mgemm128_k(
    const u16* __restrict__ A, const u16* __restrict__ Bt,
    float* C0, u16* Cb, int M, int N, int K)
{
  constexpr int TS = 128, BK = 64;
  constexpr int BUF = TS * BK;
  __shared__ __align__(16) u16 As[2 * BUF];
  __shared__ __align__(16) u16 Bs[2 * BUF];
  const int tid = threadIdx.x;
  const int l = tid & 63, lr = l & 15, lq = l >> 4;
  const int w = tid >> 6, wr = w >> 1, wc = w & 1;
  const int bm = blockIdx.y * TS, bn = blockIdx.x * TS;

  f32x4 acc[4][4];
  #pragma unroll
  for (int i = 0; i < 4; ++i)
    #pragma unroll
    for (int j = 0; j < 4; ++j) acc[i][j] = f32x4{0.f, 0.f, 0.f, 0.f};

  auto stage = [&](int k0, int buf) {
    u16* dA = As + buf * BUF;
    u16* dB = Bs + buf * BUF;
    #pragma unroll
    for (int i = 0; i < 4; ++i) {
      int e = i * 256 + tid;
      int r = e >> 3, c = (e & 7) ^ (r & 7);
      llds16(A  + (size_t)(bm + r) * K + k0 + c * 8, dA + e * 8);
      llds16(Bt + (size_t)(bn + r) * K + k0 + c * 8, dB + e * 8);
    }
  };

  stage(0, 0);
  drain_barrier();
  const int nt = K / BK;
  int cur = 0;
  for (int t = 0; t < nt; ++t) {
    if (t + 1 < nt) stage((t + 1) * BK, cur ^ 1);
    const u16* sA = As + cur * BUF;
    const u16* sB = Bs + cur * BUF;
    #pragma unroll
    for (int kk = 0; kk < 2; ++kk) {
      bf16x8 av[4], bv[4];
      #pragma unroll
      for (int m = 0; m < 4; ++m) {
        int r = wr * 64 + m * 16 + lr;
        int c = (kk * 4 + lq) ^ (r & 7);
        av[m] = *reinterpret_cast<const bf16x8*>(&sA[r * BK + c * 8]);
      }
      #pragma unroll
      for (int n = 0; n < 4; ++n) {
        int r = wc * 64 + n * 16 + lr;
        int c = (kk * 4 + lq) ^ (r & 7);
        bv[n] = *reinterpret_cast<const bf16x8*>(&sB[r * BK + c * 8]);
      }
      #pragma unroll
      for (int m = 0; m < 4; ++m)
        #pragma unroll
        for (int n = 0; n < 4; ++n)
          acc[m][n] = __builtin_amdgcn_mfma_f32_16x16x32_bf16(av[m], bv[n], acc[m][n], 0, 0, 0);
    }
    drain_barrier();
    cur ^= 1;
  }

  #pragma unroll
  for (int m = 0; m < 4; ++m) {
    int gr0 = bm + wr * 64 + m * 16 + lq * 4;
    #pragma unroll
    for (int n = 0; n < 4; ++n) {
      int gc = bn + wc * 64 + n * 16 + lr;
      #pragma unroll
      for (int q = 0; q < 4; ++q) {
        size_t idx = (size_t)(gr0 + q) * N + gc;
        float v = acc[m][n][q];
        if (EPI == 0) C0[idx] = v;
        else          Cb[idx] = f2bf(siluf_(v));
      }
    }
  }
}

// init: prep (blk 0-511) + w1^T (blk 512-639) + converts (blk 640-1151)
__global__ __launch_bounds__(256) void init_k(
    const float* __restrict__ x,
    const float* __restrict__ aw, const float* __restrict__ ab,
    const float* __restrict__ tw, const float* __restrict__ tb,
    const float* __restrict__ ew, const float* __restrict__ eb,
    const float* __restrict__ wq, const float* __restrict__ wkw,
    const float* __restrict__ wvw, const float* __restrict__ mw0,
    const float* __restrict__ mw1, const float* __restrict__ mln,
    char* ws)
{
  WS S = mkws(ws);
  const int tid = threadIdx.x;
  if (blockIdx.x < 512) {
    __shared__ float red[256];
    int s = blockIdx.x;
    int ci = s >> 6, t = s & 63;
    float sa = 0.f, st = 0.f, se = 0.f;
    for (int b = 0; b < Bb; ++b) {
      const float* xr = x + ((size_t)b * Ss + s) * Dd;
      u16* dst = S.xcb + ((size_t)(ci * RowsC + b * Cc + t)) * Dd;
      for (int d = tid; d < Dd; d += 256) {
        float v = xr[d];
        dst[d] = f2bf(v);
        sa += v * aw[d]; st += v * tw[d]; se += v * ew[d];
      }
    }
    sa = block_reduce_sum(sa, red);
    st = block_reduce_sum(st, red);
    se = block_reduce_sum(se, red);
    if (tid == 0) {
      S.alv[s] = sigmoidf_(sa + Bb * ab[0]);
      S.thv[s] = sigmoidf_(st + Bb * tb[0]) * 0.01f;
      S.etv[s] = sigmoidf_(se + Bb * eb[0]);
    }
    return;
  }
  if (blockIdx.x < 640) {
    __shared__ float t[64][65];
    int tt = blockIdx.x - 512;
    int br = (tt & 7) * 64, bc = (tt >> 3) * 64;
    #pragma unroll
    for (int i = 0; i < 16; ++i) {
      int e = tid + i * 256;
      int r = e >> 6, c = e & 63;
      t[r][c] = mw1[(size_t)(br + r) * Ii + bc + c];
    }
    __syncthreads();
    #pragma unroll
    for (int i = 0; i < 16; ++i) {
      int e = tid + i * 256;
      int rr = e >> 6, cc = e & 63;
      S.w1tb[(size_t)(bc + rr) * Dd + br + cc] = f2bf(t[cc][rr]);
    }
    return;
  }
  const int i0 = (blockIdx.x - 640) * 256 + tid;
  const int stride = 512 * 256;
  for (int i = i0; i < (Dd * Dd) / 4; i += stride) {
    float4 v = ((const float4*)wkw)[i];
    ushort4 o; o.x = f2bf(v.x); o.y = f2bf(v.y); o.z = f2bf(v.z); o.w = f2bf(v.w);
    ((ushort4*)S.wkvqb)[i] = o;
    v = ((const float4*)wvw)[i];
    o.x = f2bf(v.x); o.y = f2bf(v.y); o.z = f2bf(v.z); o.w = f2bf(v.w);
    ((ushort4*)S.wkvqb)[i + (Dd * Dd) / 4] = o;
    v = ((const float4*)wq)[i];
    o.x = f2bf(v.x); o.y = f2bf(v.y); o.z = f2bf(v.z); o.w = f2bf(v.w);
    ((ushort4*)S.wkvqb)[i + (Dd * Dd) / 2] = o;
  }
  for (int i = i0; i < (Ii * Dd) / 4; i += stride) {
    float4 z4; z4.x = z4.y = z4.z = z4.w = 0.f;
    float4 v = ((const float4*)mw0)[i];
    ((float4*)S.w0c)[i] = v; ((float4*)S.Sw0)[i] = z4;
    ushort4 o; o.x = f2bf(v.x); o.y = f2bf(v.y); o.z = f2bf(v.z); o.w = f2bf(v.w);
    ((ushort4*)S.w0b)[i] = o;
    v = ((const float4*)mw1)[i];
    ((float4*)S.w1c)[i] = v; ((float4*)S.Sw1)[i] = z4;
    o.x = f2bf(v.x); o.y = f2bf(v.y); o.z = f2bf(v.z); o.w = f2bf(v.w);
    ((ushort4*)S.w1b)[i] = o;
  }
  for (int i = i0; i < Dd; i += stride) { S.lnc[i] = mln[i]; S.Sln[i] = 0.f; }
}

// combined norms: blk 0-511 K rows (+KT), blk 512-1023 Q rows
__global__ __launch_bounds__(256) void norm2_k(
    const float* __restrict__ tmpK, const float* __restrict__ Yq,
    float* Krows, u16* Kb, u16* KT,
    float* Qb, u16* Qbb,
    const float* __restrict__ kn, const float* __restrict__ qn)
{
  __shared__ u16 lt[4][Dd];
  const int tid = threadIdx.x, w = tid >> 6, l = tid & 63;
  const bool isQ = blockIdx.x >= 512;
  const int r0 = (isQ ? (int)blockIdx.x - 512 : (int)blockIdx.x) * 4;
  const int row = r0 + w, d0 = l * 8;
  const float* in = (isQ ? Yq : tmpK) + (size_t)row * Dd + d0;
  const float* nw = (isQ ? qn : kn) + d0;
  float v[8];
  *(float4*)&v[0] = *(const float4*)in;
  *(float4*)&v[4] = *(const float4*)(in + 4);
  float ss = 0.f;
  #pragma unroll
  for (int j = 0; j < 8; ++j) { v[j] = siluf_(v[j]); ss += v[j] * v[j]; }
  ss = wave_sum(ss);
  float rr = rsqrtf(ss / (float)Dd + EPS);
  float nv[8];
  *(float4*)&nv[0] = *(const float4*)nw;
  *(float4*)&nv[4] = *(const float4*)(nw + 4);
  float y[8]; u16x8 pb;
  #pragma unroll
  for (int j = 0; j < 8; ++j) { y[j] = v[j] * rr * nv[j]; pb[j] = f2bf(y[j]); }
  float* outf = (isQ ? Qb : Krows) + (size_t)row * Dd + d0;
  u16* outb = (isQ ? Qbb : Kb) + (size_t)row * Dd + d0;
  *(float4*)outf       = *(float4*)&y[0];
  *(float4*)(outf + 4) = *(float4*)&y[4];
  *(u16x8*)outb = pb;
  if (!isQ) {
    int ci = r0 >> 8, rloc = r0 & 255;
    u16* KTc = KT + (size_t)ci * Dd * RowsC;
    #pragma unroll
    for (int j = 0; j < 8; ++j) lt[w][d0 + j] = pb[j];
    __syncthreads();
    for (int d = tid; d < Dd; d += 256) {
      ushort4 pk;
      pk.x = lt[0][d]; pk.y = lt[1][d]; pk.z = lt[2][d]; pk.w = lt[3][d];
      *reinterpret_cast<ushort4*>(&KTc[(size_t)d * RowsC + rloc]) = pk;
    }
  }
}

// wave-per-row loss backward
__global__ __launch_bounds__(256) void loss_back4_k(
    const float* __restrict__ Kr, const float* __restrict__ Vr,
    const float* __restrict__ Y, const float* __restrict__ lnc,
    const float* __restrict__ th, const float* __restrict__ wB,
    const float* __restrict__ wE,
    u16* __restrict__ dYb, u16* __restrict__ dYtW, u16* __restrict__ dYtE,
    float* __restrict__ gyr)
{
  __shared__ u16 lw[4][Dd];
  __shared__ u16 le[4][Dd];
  const int tid = threadIdx.x, w = tid >> 6, l = tid & 63;
  const int row = blockIdx.x * 4 + w, t = row & 63, d0 = l * 8;
  size_t base = (size_t)row * Dd + d0;

  float y[8], kk[8], vv[8], lv[8];
  *(float4*)&y[0]  = *(const float4*)(Y + base);
  *(float4*)&y[4]  = *(const float4*)(Y + base + 4);
  *(float4*)&kk[0] = *(const float4*)(Kr + base);
  *(float4*)&kk[4] = *(const float4*)(Kr + base + 4);
  *(float4*)&vv[0] = *(const float4*)(Vr + base);
  *(float4*)&vv[4] = *(const float4*)(Vr + base + 4);
  *(float4*)&lv[0] = *(const float4*)(lnc + d0);
  *(float4*)&lv[4] = *(const float4*)(lnc + d0 + 4);

  float ss = 0.f;
  #pragma unroll
  for (int q = 0; q < 8; ++q) ss += y[q] * y[q];
  ss = wave_sum(ss);
  float rr = rsqrtf(ss / (float)Dd + EPS);
  float c = 2.f * th[t] / (float)Dd;

  float g[8], s2 = 0.f;
  #pragma unroll
  for (int q = 0; q < 8; ++q) {
    g[q] = c * ((kk[q] + y[q] * rr * lv[q]) - vv[q]);
    s2 += g[q] * lv[q] * y[q];
  }
  s2 = wave_sum(s2);
  float coef = rr * rr * rr * s2 / (float)Dd;

  float wb = wB[row], we = wE[row];
  u16x8 pb; float gy[8];
  #pragma unroll
  for (int q = 0; q < 8; ++q) {
    float dv = rr * g[q] * lv[q] - coef * y[q];
    pb[q] = f2bf(dv);
    lw[w][d0 + q] = f2bf(dv * wb);
    le[w][d0 + q] = f2bf(dv * we);
    gy[q] = g[q] * y[q] * rr;
  }
  *(u16x8*)(dYb + base) = pb;
  *(float4*)(gyr + base)     = *(float4*)&gy[0];
  *(float4*)(gyr + base + 4) = *(float4*)&gy[4];

  __syncthreads();
  int r0 = blockIdx.x * 4;
  for (int d = tid; d < Dd; d += 256) {
    ushort4 pw, pe;
    pw.x = lw[0][d]; pw.y = lw[1][d]; pw.z = lw[2][d]; pw.w = lw[3][d];
    pe.x = le[0][d]; pe.y = le[1][d]; pe.z = le[2][d]; pe.w = le[3][d];
    *reinterpret_cast<ushort4*>(&dYtW[(size_t)d * RowsC + r0]) = pw;
    *reinterpret_cast<ushort4*>(&dYtE[(size_t)d * RowsC + r0]) = pe;
  }
}

// out[orig] = q + rms(y)*ln  (wave per row, permute back)
__global__ __launch_bounds__(256) void final4_k(
    const float* __restrict__ Q, const float* __restrict__ Y,
    const float* __restrict__ lnc, float* __restrict__ out)
{
  const int tid = threadIdx.x, w = tid >> 6, l = tid & 63;
  const int row = blockIdx.x * 4 + w;
  const int ci = row >> 8, wi = row & 255, b = wi >> 6, t = wi & 63;
  const int d0 = l * 8;
  const float* yr = Y + (size_t)row * Dd + d0;
  float y[8];
  *(float4*)&y[0] = *(const float4*)yr;
  *(float4*)&y[4] = *(const float4*)(yr + 4);
  float ss = 0.f;
  #pragma unroll
  for (int q = 0; q < 8; ++q) ss += y[q] * y[q];
  ss = wave_sum(ss);
  float rr = rsqrtf(ss / (float)Dd + EPS);
  const float* qb = Q + (size_t)row * Dd + d0;
  const float* lf = lnc + d0;
  float o[8];
  #pragma unroll
  for (int q = 0; q < 8; ++q) o[q] = qb[q] + y[q] * rr * lf[q];
  float* ob = out + ((size_t)b * Ss + ci * Cc + t) * Dd + d0;
  *(float4*)ob       = *(float4*)&o[0];
  *(float4*)(ob + 4) = *(float4*)&o[4];
}

} // namespace

extern "C" void kernel_launch(void* const* d_in, const int* in_sizes, int n_in,
                              void* d_out, int out_size, void* d_ws, size_t ws_size,
                              hipStream_t stream)
{
  const float* x   = (const float*)d_in[0];
  const float* wq  = (const float*)d_in[1];
  const float* wkw = (const float*)d_in[2];
  const float* wvw = (const float*)d_in[3];
  const float* qn  = (const float*)d_in[4];
  const float* kn  = (const float*)d_in[5];
  const float* aw  = (const float*)d_in[6];
  const float* ab  = (const float*)d_in[7];
  const float* tw  = (const float*)d_in[8];
  const float* tb  = (const float*)d_in[9];
  const float* ew  = (const float*)d_in[10];
  const float* eb  = (const float*)d_in[11];
  const float* mw0 = (const float*)d_in[12];
  const float* mw1 = (const float*)d_in[13];
  const float* mln = (const float*)d_in[14];
  float* out = (float*)d_out;
  char* ws = (char*)d_ws;
  WS S = mkws(ws);

  // ---- init (prep + transpose + converts), then gate scans inside kvq ----
  init_k<<<1152, 256, 0, stream>>>(x, aw, ab, tw, tb, ew, eb,
                                   wq, wkw, wvw, mw0, mw1, mln, ws);
  kvq_k<<<776, 256, 0, stream>>>(S.xcb, S.wkvqb, S.tmpK, S.Vrows, S.Yr, ws);
  norm2_k<<<1024, 256, 0, stream>>>(S.tmpK, S.Yr, S.Krows, S.Kb, S.KT,
                                    S.Qb, S.Qbb, kn, qn);

  // ---- sequential chunk loop: 5 launches per chunk ----
  for (int ci = 0; ci < nCk; ++ci) {
    const int p = ci & 1;
    const u16* Kbc = S.Kb + (size_t)ci * RowsC * Dd;
    const u16* KTc = S.KT + (size_t)ci * Dd * RowsC;
    const float* Krc = S.Krows + (size_t)ci * RowsC * Dd;
    const float* Vrc = S.Vrows + (size_t)ci * RowsC * Dd;
    const float* scc = S.scal + ci * 4;
    const float* wBc = S.wBv + ci * RowsC;
    const float* wEc = S.wEv + ci * RowsC;
    const float* thc = S.thv + ci * Cc;
    u16* w1b_cur = S.w1b + (size_t)p * Dd * Ii;
    u16* w1b_new = S.w1b + (size_t)(p ^ 1) * Dd * Ii;
    u16* w1t_cur = S.w1tb + (size_t)p * Ii * Dd;
    u16* w1t_new = S.w1tb + (size_t)(p ^ 1) * Ii * Dd;

    z0_k<<<dim3(Ii / 64, RowsC / 64), 256, 0, stream>>>(
        Kbc, S.w0b, S.Hb, S.Ht, S.dZb);
    y_k<<<dim3(Dd / 64, RowsC / 64), 256, 0, stream>>>(
        S.Hb, w1b_cur, S.Ybuf);
    loss_back4_k<<<RowsC / 4, 256, 0, stream>>>(
        Krc, Vrc, S.Ybuf, S.lnc, thc, wBc, wEc, S.dYb, S.dYtW, S.dYtE, S.gyr);
    s4_k<<<194, 256, 0, stream>>>(
        S.dYb, w1t_cur, S.dZb, S.dHtW, S.dHtE, S.gyr, S.lnc, S.Sln,
        S.dYtW, S.dYtE, S.Ht, S.w1c, S.Sw1, w1b_new, w1t_new,
        wBc, wEc, scc);
    g2b_k<<<128, 256, 0, stream>>>(
        S.dHtW, S.dHtE, KTc, S.w0c, S.Sw0, S.w0b, scc);
  }

  // ---- retrieval through final memory (final w1 copy is slot 0) ----
  mgemm128_k<4><<<dim3(Ii / 128, RowsAll / 128), 256, 0, stream>>>(
      S.Qbb, S.w0b, nullptr, S.Hrb, RowsAll, Ii, Dd);
  mgemm128_k<0><<<dim3(Dd / 128, RowsAll / 128), 256, 0, stream>>>(
      S.Hrb, S.w1b, S.Yr, nullptr, RowsAll, Dd, Ii);
  final4_k<<<RowsAll / 4, 256, 0, stream>>>(S.Qb, S.Yr, S.lnc, out);
}